// Round 5
// baseline (5850.281 us; speedup 1.0000x reference)
//
#include <hip/hip_runtime.h>
#include <hip/hip_bf16.h>
#include <math.h>

#define B_    128
#define L_    128
#define DIN   6
#define D_    256
#define H_    8
#define NL_   6
#define NE_   8
#define DFF_  1024
#define NOUT_ 5
#define T_    (B_*L_)      /* 16384 tokens */
#define DK_   32
#define CH_   256          /* DFF chunk for MoE hidden buffer */

typedef unsigned short u16;
typedef __hip_bfloat16 bf16;

// element-offset prefix of the 21 inputs inside the canonical f32 region
static constexpr int H_PRE[22] = {
    0, 98304, 99840, 100096, 493312, 886528, 1279744, 1672960,
    1673008, 1673056, 1679200, 1679224, 7970680, 7995256, 14286712,
    14292856, 14293112, 14293368, 14294648, 14294653, 14295933, 14295938};
__device__ const int d_PRE[22] = {
    0, 98304, 99840, 100096, 493312, 886528, 1279744, 1672960,
    1673008, 1673056, 1679200, 1679224, 7970680, 7995256, 14286712,
    14292856, 14293112, 14293368, 14294648, 14294653, 14295933, 14295938};
#define NTOT_CANON 14295938

struct SrcPtrs { const void* p[21]; };

__device__ __forceinline__ float bf2f(u16 u) {
    return __uint_as_float(((unsigned)u) << 16);
}
__device__ __forceinline__ u16 f2bf(float f) {
    union { bf16 b; u16 u; } c; c.b = __float2bfloat16(f); return c.u;
}
__device__ __forceinline__ float gelu_f(float x) {
    return 0.5f * x * (1.0f + erff(x * 0.70710678118654752f));
}

// ---------------------------------------------------------------------------
// Canonicalize all inputs to f32. Runtime dtype probe: ln_g is all ones;
// first u16 == 0x3F80 iff tensors are bf16, 0x0000 iff float32.
// ---------------------------------------------------------------------------
__global__ __launch_bounds__(256)
void conv_kernel(SrcPtrs P, float* __restrict__ dst, int total)
{
    const int i = blockIdx.x * 256 + threadIdx.x;
    if (i >= total) return;
    int seg = 0;
    #pragma unroll
    for (int s = 1; s < 21; ++s) seg += (i >= d_PRE[s]) ? 1 : 0;
    const int off = i - d_PRE[seg];
    const bool isbf = (((const u16*)P.p[15])[0] == 0x3F80);
    if (isbf) dst[i] = bf2f(((const u16*)P.p[seg])[off]);
    else      dst[i] = ((const float*)P.p[seg])[off];
}

// ---------------------------------------------------------------------------
// Embedding: h[t,d] = sum_j x[t,j]*emb_w[j,d] + emb_b[d]   (all f32)
// ---------------------------------------------------------------------------
__global__ __launch_bounds__(256)
void embed_kernel(const float* __restrict__ x, const float* __restrict__ emb_w,
                  const float* __restrict__ emb_b, float* __restrict__ h)
{
    const int idx = blockIdx.x * 256 + threadIdx.x;
    const int t = idx >> 8;
    const int d = idx & 255;
    float acc = emb_b[d];
    #pragma unroll
    for (int j = 0; j < DIN; ++j)
        acc += x[t * DIN + j] * emb_w[j * D_ + d];
    h[idx] = acc;
}

// ---------------------------------------------------------------------------
// 128x128 tile GEMM: C = A[AT, MxK] @ W[f32, K x Ncols]
// EPI 0: store bf16              (q/k/v projections)
// EPI 1: accumulate into f32 C   (out-proj residual; A is bf16 ob)
// EPI 2: +bias, gelu, f32 store at gathered slot (MoE w1, col-chunked)
// EPI 3: +bias(opt), *aw, atomicAdd f32 scatter by token into moeout (MoE w2)
// GATHER: A rows via atok[ebase[z]+row]
// cshift: global W/bias col = blockIdx.y*128 + cshift; C col is local
// ---------------------------------------------------------------------------
template<int EPI, bool GATHER, typename AT>
__global__ __launch_bounds__(256)
void gemm_bigtile(const AT* __restrict__ A, int lda, int K,
                  const float* __restrict__ Wb, long wzs, int ldw,
                  const float* __restrict__ biasb, long bzs,
                  void* __restrict__ CoutV, int ldc, int cshift,
                  int Mfixed,
                  const int*  __restrict__ cnt,
                  const int*  __restrict__ ebase,
                  const int*  __restrict__ atok,
                  const float* __restrict__ aw)
{
    const int z  = blockIdx.z;
    const int M  = cnt ? cnt[z] : Mfixed;
    const int r0 = blockIdx.x * 128;
    if (r0 >= M) return;
    const int rowbase = ebase ? ebase[z] : 0;
    const float* W    = Wb + (size_t)z * wzs;
    const float* bias = biasb ? (biasb + (size_t)z * bzs) : nullptr;
    const int col0 = blockIdx.y * 128 + cshift;

    __shared__ float As[8][132];
    __shared__ float Bs[8][128];
    __shared__ int   stok[128];

    const int tid = threadIdx.x;
    if (GATHER) {
        if (tid < 128) {
            int rr = r0 + tid;
            stok[tid] = (rr < M) ? atok[rowbase + rr] : 0;
        }
        __syncthreads();
    }

    const int tx = tid & 15, ty = tid >> 4;
    const int ar = tid >> 1, ak4 = (tid & 1) * 4;
    const int bk = tid >> 5, bc4 = (tid & 31) * 4;

    float acc[8][8];
    #pragma unroll
    for (int i = 0; i < 8; ++i)
        #pragma unroll
        for (int j = 0; j < 8; ++j) acc[i][j] = 0.0f;

    const int growA = r0 + ar;
    const bool rokA = (growA < M);
    long arow;
    if (GATHER) arow = rokA ? (long)stok[ar] : 0;
    else        arow = (long)rowbase + growA;
    const AT*    aptr = A + arow * (long)lda + ak4;
    const float* wptr = W + (size_t)bk * ldw + col0 + bc4;

    for (int k0 = 0; k0 < K; k0 += 8) {
        float4 av = make_float4(0.f, 0.f, 0.f, 0.f);
        if (rokA) {
            if constexpr (sizeof(AT) == 4) {
                av = *(const float4*)(aptr + k0);
            } else {
                ushort4 t = *(const ushort4*)(aptr + k0);
                av = make_float4(bf2f(t.x), bf2f(t.y), bf2f(t.z), bf2f(t.w));
            }
        }
        As[ak4 + 0][ar] = av.x;
        As[ak4 + 1][ar] = av.y;
        As[ak4 + 2][ar] = av.z;
        As[ak4 + 3][ar] = av.w;
        float4 wv = *(const float4*)(wptr + (size_t)k0 * ldw);
        Bs[bk][bc4 + 0] = wv.x;
        Bs[bk][bc4 + 1] = wv.y;
        Bs[bk][bc4 + 2] = wv.z;
        Bs[bk][bc4 + 3] = wv.w;
        __syncthreads();
        #pragma unroll
        for (int kk = 0; kk < 8; ++kk) {
            float4 a0 = *(const float4*)&As[kk][ty * 4];
            float4 a1 = *(const float4*)&As[kk][64 + ty * 4];
            float4 b0 = *(const float4*)&Bs[kk][tx * 4];
            float4 b1 = *(const float4*)&Bs[kk][64 + tx * 4];
            float a[8] = {a0.x, a0.y, a0.z, a0.w, a1.x, a1.y, a1.z, a1.w};
            float b[8] = {b0.x, b0.y, b0.z, b0.w, b1.x, b1.y, b1.z, b1.w};
            #pragma unroll
            for (int i = 0; i < 8; ++i)
                #pragma unroll
                for (int j = 0; j < 8; ++j)
                    acc[i][j] = fmaf(a[i], b[j], acc[i][j]);
        }
        __syncthreads();
    }

    #pragma unroll
    for (int ih = 0; ih < 2; ++ih) {
        #pragma unroll
        for (int ii = 0; ii < 4; ++ii) {
            const int lr = ih * 64 + ty * 4 + ii;
            const int grow = r0 + lr;
            if (grow >= M) continue;
            const int i = ih * 4 + ii;
            #pragma unroll
            for (int jh = 0; jh < 2; ++jh) {
                const int cj = col0 + jh * 64 + tx * 4;   // global W/bias col
                const int cl = cj - cshift;               // local C col
                float4 vv;
                vv.x = acc[i][jh * 4 + 0];
                vv.y = acc[i][jh * 4 + 1];
                vv.z = acc[i][jh * 4 + 2];
                vv.w = acc[i][jh * 4 + 3];
                if constexpr (EPI == 0) {
                    u16* C = (u16*)CoutV;
                    ushort4 sv = make_ushort4(f2bf(vv.x), f2bf(vv.y),
                                              f2bf(vv.z), f2bf(vv.w));
                    *(ushort4*)(&C[(long)grow * ldc + cl]) = sv;
                } else if constexpr (EPI == 1) {
                    float* C = (float*)CoutV;
                    float4 old = *(const float4*)(&C[(long)grow * ldc + cl]);
                    vv.x += old.x; vv.y += old.y; vv.z += old.z; vv.w += old.w;
                    *(float4*)(&C[(long)grow * ldc + cl]) = vv;
                } else if constexpr (EPI == 2) {
                    float* C = (float*)CoutV;
                    const long slot = (long)rowbase + grow;
                    float4 sv;
                    sv.x = gelu_f(vv.x + bias[cj + 0]);
                    sv.y = gelu_f(vv.y + bias[cj + 1]);
                    sv.z = gelu_f(vv.z + bias[cj + 2]);
                    sv.w = gelu_f(vv.w + bias[cj + 3]);
                    *(float4*)(&C[slot * ldc + cl]) = sv;
                } else {
                    float* C = (float*)CoutV;
                    const long slot = (long)rowbase + grow;
                    const int tkn = atok[slot];
                    const float w = aw[slot];
                    float b0 = bias ? bias[cj + 0] : 0.0f;
                    float b1 = bias ? bias[cj + 1] : 0.0f;
                    float b2 = bias ? bias[cj + 2] : 0.0f;
                    float b3 = bias ? bias[cj + 3] : 0.0f;
                    float* dst = &C[(long)tkn * ldc + cl];
                    atomicAdd(dst + 0, w * (vv.x + b0));
                    atomicAdd(dst + 1, w * (vv.y + b1));
                    atomicAdd(dst + 2, w * (vv.z + b2));
                    atomicAdd(dst + 3, w * (vv.w + b3));
                }
            }
        }
    }
}

// ---------------------------------------------------------------------------
// Wave attention, one block per (b, head). q/k/v/o bf16, math f32.
// ---------------------------------------------------------------------------
__global__ __launch_bounds__(256)
void attn_kernel(const u16* __restrict__ q, const u16* __restrict__ k,
                 const u16* __restrict__ v, u16* __restrict__ o,
                 const float* __restrict__ wfreq, const float* __restrict__ wphase)
{
    const int bh = blockIdx.x;
    const int b  = bh >> 3;
    const int hh = bh & 7;

    __shared__ float ks[L_][DK_];
    __shared__ float vs[L_][DK_];
    __shared__ float wave[L_];

    const int tid = threadIdx.x;
    const long base = (long)b * L_ * D_ + hh * DK_;

    #pragma unroll
    for (int l = 0; l < 16; ++l) {
        int e = tid + l * 256;
        int row = e >> 5, dk = e & 31;
        ks[row][dk] = bf2f(k[base + (long)row * D_ + dk]);
        vs[row][dk] = bf2f(v[base + (long)row * D_ + dk]);
    }
    if (tid < L_) {
        float f2 = 6.2831853071795864769f * wfreq[hh];
        wave[tid] = cosf(f2 * (float)tid + wphase[hh]);
    }

    const int r = tid >> 1, half = tid & 1;
    float qr[32];
    {
        const ushort4* qp = (const ushort4*)(q + base + (long)r * D_);
        #pragma unroll
        for (int i4 = 0; i4 < 8; ++i4) {
            ushort4 t4 = qp[i4];
            qr[4*i4+0] = bf2f(t4.x); qr[4*i4+1] = bf2f(t4.y);
            qr[4*i4+2] = bf2f(t4.z); qr[4*i4+3] = bf2f(t4.w);
        }
    }
    __syncthreads();

    const float scale = 0.17677669529663687f;   // 1/sqrt(32)
    const int cbase = half * 64;

    float m = -1e30f;
    for (int cc = 0; cc < 64; ++cc) {
        int c = cbase + cc;
        float s = 0.0f;
        const float4* krow = (const float4*)&ks[c][0];
        #pragma unroll
        for (int i4 = 0; i4 < 8; ++i4) {
            float4 k4 = krow[i4];
            s = fmaf(qr[4*i4+0], k4.x, s);
            s = fmaf(qr[4*i4+1], k4.y, s);
            s = fmaf(qr[4*i4+2], k4.z, s);
            s = fmaf(qr[4*i4+3], k4.w, s);
        }
        s = s * scale * wave[c];
        m = fmaxf(m, s);
    }
    m = fmaxf(m, __shfl_xor(m, 1));

    float lsum = 0.0f;
    float O[32];
    #pragma unroll
    for (int i = 0; i < 32; ++i) O[i] = 0.0f;
    for (int cc = 0; cc < 64; ++cc) {
        int c = cbase + cc;
        float s = 0.0f;
        const float4* krow = (const float4*)&ks[c][0];
        #pragma unroll
        for (int i4 = 0; i4 < 8; ++i4) {
            float4 k4 = krow[i4];
            s = fmaf(qr[4*i4+0], k4.x, s);
            s = fmaf(qr[4*i4+1], k4.y, s);
            s = fmaf(qr[4*i4+2], k4.z, s);
            s = fmaf(qr[4*i4+3], k4.w, s);
        }
        s = s * scale * wave[c];
        float e = expf(s - m);
        lsum += e;
        const float4* vrow = (const float4*)&vs[c][0];
        #pragma unroll
        for (int i4 = 0; i4 < 8; ++i4) {
            float4 v4 = vrow[i4];
            O[4*i4+0] = fmaf(e, v4.x, O[4*i4+0]);
            O[4*i4+1] = fmaf(e, v4.y, O[4*i4+1]);
            O[4*i4+2] = fmaf(e, v4.z, O[4*i4+2]);
            O[4*i4+3] = fmaf(e, v4.w, O[4*i4+3]);
        }
    }
    lsum += __shfl_xor(lsum, 1);
    const float inv = 1.0f / lsum;

    #pragma unroll
    for (int j = 0; j < 16; ++j) {
        float a0 = O[j]      + __shfl_xor(O[j], 1);
        float a1 = O[16 + j] + __shfl_xor(O[16 + j], 1);
        float val = (half ? a1 : a0) * inv;
        o[base + (long)r * D_ + half * 16 + j] = f2bf(val);
    }
}

// ---------------------------------------------------------------------------
// MoE router (all f32): logits -> top2 -> normalized weights; expert counts.
// ---------------------------------------------------------------------------
__global__ __launch_bounds__(256)
void router_kernel(const float* __restrict__ h, const float* __restrict__ rtw,
                   const float* __restrict__ rtb, int* __restrict__ te,
                   float* __restrict__ twt, int* __restrict__ cnt)
{
    const int t = blockIdx.x * 256 + threadIdx.x;
    float lg[NE_];
    #pragma unroll
    for (int e = 0; e < NE_; ++e) lg[e] = rtb[e];
    const float4* rp = (const float4*)rtw;
    const float* hr = h + (long)t * D_;
    for (int d = 0; d < D_; ++d) {
        float xv = hr[d];
        float4 wa = rp[d * 2 + 0];
        float4 wb = rp[d * 2 + 1];
        lg[0] = fmaf(xv, wa.x, lg[0]);
        lg[1] = fmaf(xv, wa.y, lg[1]);
        lg[2] = fmaf(xv, wa.z, lg[2]);
        lg[3] = fmaf(xv, wa.w, lg[3]);
        lg[4] = fmaf(xv, wb.x, lg[4]);
        lg[5] = fmaf(xv, wb.y, lg[5]);
        lg[6] = fmaf(xv, wb.z, lg[6]);
        lg[7] = fmaf(xv, wb.w, lg[7]);
    }
    int i1 = 0; float v1 = lg[0];
    #pragma unroll
    for (int e = 1; e < NE_; ++e) { if (lg[e] > v1) { v1 = lg[e]; i1 = e; } }
    int i2 = (i1 == 0) ? 1 : 0; float v2 = lg[i2];
    #pragma unroll
    for (int e = 0; e < NE_; ++e) {
        if (e != i1 && lg[e] > v2) { v2 = lg[e]; i2 = e; }
    }
    float r   = expf(v2 - v1);
    float wa1 = 1.0f / (1.0f + r);
    float wa2 = r * wa1;
    te[2 * t]     = i1;
    te[2 * t + 1] = i2;
    twt[2 * t]     = wa1;
    twt[2 * t + 1] = wa2;
    atomicAdd(&cnt[i1], 1);
    atomicAdd(&cnt[i2], 1);
}

__global__ void zero8_kernel(int* cnt) {
    if (threadIdx.x < NE_) cnt[threadIdx.x] = 0;
}

__global__ void scan_kernel(const int* __restrict__ cnt, int* __restrict__ base_,
                            int* __restrict__ cursor)
{
    if (threadIdx.x == 0) {
        int a = 0;
        for (int e = 0; e < NE_; ++e) { base_[e] = a; a += cnt[e]; }
        base_[NE_] = a;
    }
    if (threadIdx.x < NE_) cursor[threadIdx.x] = 0;
}

__global__ __launch_bounds__(256)
void scatter_kernel(const int* __restrict__ te, const float* __restrict__ twt,
                    const int* __restrict__ base_, int* __restrict__ cursor,
                    int* __restrict__ atok, float* __restrict__ aw)
{
    const int t = blockIdx.x * 256 + threadIdx.x;
    #pragma unroll
    for (int kk = 0; kk < 2; ++kk) {
        int e = te[2 * t + kk];
        int pos = atomicAdd(&cursor[e], 1);
        int slot = base_[e] + pos;
        atok[slot] = t;
        aw[slot] = twt[2 * t + kk];
    }
}

__global__ __launch_bounds__(256)
void zerof_kernel(float* __restrict__ p)
{
    p[blockIdx.x * 256 + threadIdx.x] = 0.0f;
}

__global__ __launch_bounds__(256)
void addinto_kernel(float* __restrict__ dst, const float* __restrict__ src)
{
    const int i = blockIdx.x * 256 + threadIdx.x;
    dst[i] += src[i];
}

// ---------------------------------------------------------------------------
// Final: layernorm on last-position tokens only, then pred / softplus heads.
// OUTPUT IS FLOAT32 (the reference's output dtype).
// ---------------------------------------------------------------------------
__global__ __launch_bounds__(256)
void final_kernel(const float* __restrict__ h, const float* __restrict__ ln_g,
                  const float* __restrict__ ln_b, const float* __restrict__ pred_w,
                  const float* __restrict__ pred_b, const float* __restrict__ unc_w,
                  const float* __restrict__ unc_b, float* __restrict__ out)
{
    const int b = blockIdx.x;
    const int d = threadIdx.x;
    const long t = (long)b * L_ + (L_ - 1);
    const float val = h[t * D_ + d];

    __shared__ float red[4];
    __shared__ float lat[D_];

    float s = val;
    #pragma unroll
    for (int off = 32; off > 0; off >>= 1) s += __shfl_down(s, off);
    if ((d & 63) == 0) red[d >> 6] = s;
    __syncthreads();
    const float mean = (red[0] + red[1] + red[2] + red[3]) * (1.0f / D_);
    __syncthreads();

    const float dv = val - mean;
    s = dv * dv;
    #pragma unroll
    for (int off = 32; off > 0; off >>= 1) s += __shfl_down(s, off);
    if ((d & 63) == 0) red[d >> 6] = s;
    __syncthreads();
    const float var = (red[0] + red[1] + red[2] + red[3]) * (1.0f / D_);

    lat[d] = dv * rsqrtf(var + 1e-5f) * ln_g[d] + ln_b[d];
    __syncthreads();

    if (d < 2 * NOUT_) {
        const int j = d % NOUT_;
        const int sel = d / NOUT_;
        const float* w  = sel ? unc_w : pred_w;
        const float* bb = sel ? unc_b : pred_b;
        float acc = bb[j];
        for (int dd = 0; dd < D_; ++dd)
            acc = fmaf(lat[dd], w[dd * NOUT_ + j], acc);
        if (sel) acc = log1pf(expf(acc));
        out[sel * (B_ * NOUT_) + b * NOUT_ + j] = acc;
    }
}

// ---------------------------------------------------------------------------
extern "C" void kernel_launch(void* const* d_in, const int* in_sizes, int n_in,
                              void* d_out, int out_size, void* d_ws, size_t ws_size,
                              hipStream_t stream)
{
    (void)in_sizes; (void)n_in; (void)out_size; (void)ws_size;

    // workspace layout (256B aligned); ~159 MB total
    char* ws = (char*)d_ws;
    size_t off = 0;
    auto alloc = [&](size_t bytes) {
        size_t cur = off;
        off += (bytes + 255) & ~(size_t)255;
        return (void*)(ws + cur);
    };
    float* canon  = (float*)alloc((size_t)NTOT_CANON * 4);           // 57.2 MB
    float* h      = (float*)alloc((size_t)T_ * D_ * 4);              // 16.8 MB
    u16*   qb     = (u16*)  alloc((size_t)T_ * D_ * 2);              //  8.4 MB
    u16*   kb     = (u16*)  alloc((size_t)T_ * D_ * 2);
    u16*   vb     = (u16*)  alloc((size_t)T_ * D_ * 2);
    u16*   ob     = (u16*)  alloc((size_t)T_ * D_ * 2);
    float* hidden = (float*)alloc((size_t)2 * T_ * CH_ * 4);         // 33.6 MB
    float* moeout = (float*)alloc((size_t)T_ * D_ * 4);              // 16.8 MB
    int*   te     = (int*)  alloc((size_t)2 * T_ * 4);
    float* twt    = (float*)alloc((size_t)2 * T_ * 4);
    int*   atok   = (int*)  alloc((size_t)2 * T_ * 4);
    float* aw     = (float*)alloc((size_t)2 * T_ * 4);
    int*   cnt    = (int*)  alloc(64 * 4);
    int*   base_  = (int*)  alloc(64 * 4);
    int*   cursor = (int*)  alloc(64 * 4);

    // canonicalize inputs to f32 (upcast bf16 or copy f32, probed on device)
    SrcPtrs P;
    for (int i = 0; i < 21; ++i) P.p[i] = d_in[i];
    conv_kernel<<<(NTOT_CANON + 255) / 256, 256, 0, stream>>>(P, canon, NTOT_CANON);

    const float* x      = canon + H_PRE[0];
    const float* emb_w  = canon + H_PRE[1];
    const float* emb_b  = canon + H_PRE[2];
    const float* wq     = canon + H_PRE[3];
    const float* wk     = canon + H_PRE[4];
    const float* wv     = canon + H_PRE[5];
    const float* wo     = canon + H_PRE[6];
    const float* wfreq  = canon + H_PRE[7];
    const float* wphase = canon + H_PRE[8];
    const float* rtw    = canon + H_PRE[9];
    const float* rtb    = canon + H_PRE[10];
    const float* ew1    = canon + H_PRE[11];
    const float* eb1    = canon + H_PRE[12];
    const float* ew2    = canon + H_PRE[13];
    const float* eb2    = canon + H_PRE[14];
    const float* ln_g   = canon + H_PRE[15];
    const float* ln_b   = canon + H_PRE[16];
    const float* pred_w = canon + H_PRE[17];
    const float* pred_b = canon + H_PRE[18];
    const float* unc_w  = canon + H_PRE[19];
    const float* unc_b  = canon + H_PRE[20];

    embed_kernel<<<(T_ * D_) / 256, 256, 0, stream>>>(x, emb_w, emb_b, h);

    const dim3 gP(T_ / 128, D_ / 128, 1);
    for (int i = 0; i < NL_; ++i) {
        const size_t woff = (size_t)i * D_ * D_;
        gemm_bigtile<0, false, float><<<gP, 256, 0, stream>>>(
            h, D_, D_, wq + woff, 0, D_, nullptr, 0, qb, D_, 0, T_,
            nullptr, nullptr, nullptr, nullptr);
        gemm_bigtile<0, false, float><<<gP, 256, 0, stream>>>(
            h, D_, D_, wk + woff, 0, D_, nullptr, 0, kb, D_, 0, T_,
            nullptr, nullptr, nullptr, nullptr);
        gemm_bigtile<0, false, float><<<gP, 256, 0, stream>>>(
            h, D_, D_, wv + woff, 0, D_, nullptr, 0, vb, D_, 0, T_,
            nullptr, nullptr, nullptr, nullptr);
        attn_kernel<<<B_ * H_, 256, 0, stream>>>(qb, kb, vb, ob,
                                                 wfreq + i * H_, wphase + i * H_);
        gemm_bigtile<1, false, u16><<<gP, 256, 0, stream>>>(
            ob, D_, D_, wo + woff, 0, D_, nullptr, 0, h, D_, 0, T_,
            nullptr, nullptr, nullptr, nullptr);

        if (i % 2 == 0) {
            const int m = i / 2;
            zero8_kernel<<<1, 64, 0, stream>>>(cnt);
            router_kernel<<<T_ / 256, 256, 0, stream>>>(
                h, rtw + (size_t)m * D_ * NE_, rtb + m * NE_, te, twt, cnt);
            scan_kernel<<<1, 64, 0, stream>>>(cnt, base_, cursor);
            scatter_kernel<<<T_ / 256, 256, 0, stream>>>(te, twt, base_, cursor,
                                                         atok, aw);
            zerof_kernel<<<(T_ * D_) / 256, 256, 0, stream>>>(moeout);
            for (int c = 0; c < DFF_ / CH_; ++c) {
                gemm_bigtile<2, true, float><<<dim3(128, CH_ / 128, NE_), 256, 0, stream>>>(
                    h, D_, D_,
                    ew1 + (size_t)m * NE_ * D_ * DFF_, (long)D_ * DFF_, DFF_,
                    eb1 + (size_t)m * NE_ * DFF_, DFF_,
                    hidden, CH_, c * CH_,
                    0, cnt, base_, atok, aw);
                gemm_bigtile<3, false, float><<<dim3(128, D_ / 128, NE_), 256, 0, stream>>>(
                    hidden, CH_, CH_,
                    ew2 + (size_t)m * NE_ * DFF_ * D_ + (size_t)c * CH_ * D_,
                    (long)DFF_ * D_, D_,
                    (c == 0) ? (eb2 + (size_t)m * NE_ * D_) : nullptr, D_,
                    moeout, D_, 0,
                    0, cnt, base_, atok, aw);
            }
            addinto_kernel<<<(T_ * D_) / 256, 256, 0, stream>>>(h, moeout);
        }
    }

    final_kernel<<<B_, 256, 0, stream>>>(h, ln_g, ln_b, pred_w, pred_b,
                                         unc_w, unc_b, (float*)d_out);
}

// Round 6
// 2374.656 us; speedup vs baseline: 2.4636x; 2.4636x over previous
//
#include <hip/hip_runtime.h>
#include <hip/hip_bf16.h>
#include <math.h>

#define B_    128
#define L_    128
#define DIN   6
#define D_    256
#define H_    8
#define NL_   6
#define NE_   8
#define DFF_  1024
#define NOUT_ 5
#define T_    (B_*L_)      /* 16384 tokens */
#define DK_   32
#define CH_   512          /* DFF chunk for MoE hidden buffer */

typedef unsigned short u16;
typedef __hip_bfloat16 bf16;
typedef __attribute__((ext_vector_type(8))) short short8;
typedef __attribute__((ext_vector_type(8))) unsigned short ushort8v;
typedef __attribute__((ext_vector_type(4))) float floatx4;

// small f32 canon region: x, emb_w, emb_b, wfreq, wphase, rtw, rtb, eb1,
// eb2, ln_g, ln_b, pred_w, pred_b, unc_w, unc_b
__device__ const int S_PRE[16] = {
    0, 98304, 99840, 100096, 100144, 100192, 106336, 106360,
    130936, 137080, 137336, 137592, 138872, 138877, 140157, 140162};
__device__ const int S_SRC[15] = {0,1,2,7,8,9,10,12,14,15,16,17,18,19,20};
#define NSMALL 140162

struct SrcPtrs { const void* p[21]; };

__device__ __forceinline__ float bf2f(u16 u) {
    return __uint_as_float(((unsigned)u) << 16);
}
__device__ __forceinline__ u16 f2bf(float f) {
    union { bf16 b; u16 u; } c; c.b = __float2bfloat16(f); return c.u;
}
__device__ __forceinline__ float gelu_f(float x) {
    return 0.5f * x * (1.0f + erff(x * 0.70710678118654752f));
}

// ---------------------------------------------------------------------------
// Canonicalize small tensors to f32 (dtype probe: ln_g[0]==0x3F80 iff bf16)
// ---------------------------------------------------------------------------
__global__ __launch_bounds__(256)
void conv_small_kernel(SrcPtrs P, float* __restrict__ dst)
{
    const int i = blockIdx.x * 256 + threadIdx.x;
    if (i >= NSMALL) return;
    int seg = 0;
    #pragma unroll
    for (int s = 1; s < 15; ++s) seg += (i >= S_PRE[s]) ? 1 : 0;
    const int off = i - S_PRE[seg];
    const void* src = P.p[S_SRC[seg]];
    const bool isbf = (((const u16*)P.p[15])[0] == 0x3F80);
    if (isbf) dst[i] = bf2f(((const u16*)src)[off]);
    else      dst[i] = ((const float*)src)[off];
}

// ---------------------------------------------------------------------------
// Weight transpose+cast: dst[z][(n+noff)][k] (bf16, row len KD) = src[z][k][n]
// ---------------------------------------------------------------------------
template<int KD, int ND>
__global__ __launch_bounds__(256)
void transpose_kernel(const void* __restrict__ src, const u16* __restrict__ probe,
                      u16* __restrict__ dst, long dzs, int noff, int total)
{
    const int i = blockIdx.x * 256 + threadIdx.x;
    if (i >= total) return;
    const int z   = i / (KD * ND);
    const int rem = i - z * (KD * ND);
    const int n   = rem / KD;
    const int k   = rem - n * KD;
    const size_t si = (size_t)z * KD * ND + (size_t)k * ND + n;
    const bool isbf = (probe[0] == 0x3F80);
    const float v = isbf ? bf2f(((const u16*)src)[si]) : ((const float*)src)[si];
    dst[(size_t)z * dzs + (size_t)(n + noff) * KD + k] = f2bf(v);
}

// ---------------------------------------------------------------------------
// Embedding (all f32)
// ---------------------------------------------------------------------------
__global__ __launch_bounds__(256)
void embed_kernel(const float* __restrict__ x, const float* __restrict__ emb_w,
                  const float* __restrict__ emb_b, float* __restrict__ h)
{
    const int idx = blockIdx.x * 256 + threadIdx.x;
    const int t = idx >> 8;
    const int d = idx & 255;
    float acc = emb_b[d];
    #pragma unroll
    for (int j = 0; j < DIN; ++j)
        acc += x[t * DIN + j] * emb_w[j * D_ + d];
    h[idx] = acc;
}

// ---------------------------------------------------------------------------
// MFMA GEMM, 128x128 tile, 4 waves (each 64x64 via 16x16x32 bf16 MFMA).
// A: row-major MxK (f32 or bf16), staged->bf16 LDS.  W: bf16 W^T [N][K].
// EPI 0: store bf16 C            (fused QKV)
// EPI 1: C f32 +=                (o-proj residual)
// EPI 2: +bias, gelu -> bf16 at slot row (MoE w1)
// EPI 3: +bias -> f32 store at slot row  (MoE w2 chunk 0)
// EPI 4: f32 += at slot row              (MoE w2 chunk 1)
// GATHER: A row = atok[ebase[z] + row]
// ---------------------------------------------------------------------------
template<int EPI, bool GATHER, typename AT>
__global__ __launch_bounds__(256)
void mfma_gemm(const AT* __restrict__ A, int lda, int K,
               const u16* __restrict__ Wt, long wzs, int ldwt, int wkoff,
               const float* __restrict__ biasb, long bzs,
               void* __restrict__ CoutV, int ldc, int cshift,
               int Mfixed,
               const int* __restrict__ cnt, const int* __restrict__ ebase,
               const int* __restrict__ atok)
{
    const int z  = blockIdx.z;
    const int M  = cnt ? cnt[z] : Mfixed;
    const int r0 = blockIdx.x * 128;
    if (r0 >= M) return;
    const int rowbase = ebase ? ebase[z] : 0;
    const u16*   W    = Wt + (size_t)z * wzs;
    const float* bias = biasb ? (biasb + (size_t)z * bzs) : nullptr;
    const int col0 = blockIdx.y * 128 + cshift;

    __shared__ __attribute__((aligned(16))) u16 As[128][40];
    __shared__ __attribute__((aligned(16))) u16 Bs[128][40];
    __shared__ int stok[128];

    const int tid  = threadIdx.x;
    const int lane = tid & 63;
    const int wave = tid >> 6;
    const int wm = wave & 1, wn = wave >> 1;

    if (GATHER) {
        if (tid < 128) {
            int rr = r0 + tid;
            stok[tid] = (rr < M) ? atok[rowbase + rr] : 0;
        }
        __syncthreads();
    }

    floatx4 acc[4][4];
    #pragma unroll
    for (int i = 0; i < 4; ++i)
        #pragma unroll
        for (int j = 0; j < 4; ++j)
            acc[i][j] = (floatx4){0.f, 0.f, 0.f, 0.f};

    // staging maps: thread -> (row 0..127, k-half 0/16)
    const int sr = tid >> 1;
    const int sk = (tid & 1) * 16;
    long arow;
    if (GATHER) arow = (long)stok[sr];
    else {
        int rr = r0 + sr; if (rr >= M) rr = M - 1;
        arow = (long)rowbase + rr;
    }
    const AT*  aptr = A + arow * (long)lda + sk;
    const u16* wptr = W + (size_t)(col0 + sr) * ldwt + wkoff + sk;

    // fragment maps
    const int fm = wm * 64 + (lane & 15);
    const int fn = wn * 64 + (lane & 15);
    const int fk = (lane >> 4) * 8;

    for (int k0 = 0; k0 < K; k0 += 32) {
        // stage A -> bf16
        if constexpr (sizeof(AT) == 4) {
            const float4* ap = (const float4*)(aptr + k0);
            float4 v0 = ap[0], v1 = ap[1], v2 = ap[2], v3 = ap[3];
            ushort8v t0, t1;
            t0[0]=f2bf(v0.x); t0[1]=f2bf(v0.y); t0[2]=f2bf(v0.z); t0[3]=f2bf(v0.w);
            t0[4]=f2bf(v1.x); t0[5]=f2bf(v1.y); t0[6]=f2bf(v1.z); t0[7]=f2bf(v1.w);
            t1[0]=f2bf(v2.x); t1[1]=f2bf(v2.y); t1[2]=f2bf(v2.z); t1[3]=f2bf(v2.w);
            t1[4]=f2bf(v3.x); t1[5]=f2bf(v3.y); t1[6]=f2bf(v3.z); t1[7]=f2bf(v3.w);
            *(ushort8v*)&As[sr][sk]     = t0;
            *(ushort8v*)&As[sr][sk + 8] = t1;
        } else {
            const ushort8v* ap = (const ushort8v*)(aptr + k0);
            *(ushort8v*)&As[sr][sk]     = ap[0];
            *(ushort8v*)&As[sr][sk + 8] = ap[1];
        }
        // stage B (already bf16 W^T, k-contiguous)
        {
            const ushort8v* wp = (const ushort8v*)(wptr + k0);
            *(ushort8v*)&Bs[sr][sk]     = wp[0];
            *(ushort8v*)&Bs[sr][sk + 8] = wp[1];
        }
        __syncthreads();

        short8 af[4], bfr[4];
        #pragma unroll
        for (int i = 0; i < 4; ++i) af[i]  = *(const short8*)&As[fm + 16*i][fk];
        #pragma unroll
        for (int j = 0; j < 4; ++j) bfr[j] = *(const short8*)&Bs[fn + 16*j][fk];
        #pragma unroll
        for (int i = 0; i < 4; ++i)
            #pragma unroll
            for (int j = 0; j < 4; ++j)
                acc[i][j] = __builtin_amdgcn_mfma_f32_16x16x32_bf16(
                    af[i], bfr[j], acc[i][j], 0, 0, 0);
        __syncthreads();
    }

    // epilogue: C/D layout col=lane&15, row=(lane>>4)*4+reg
    const int er = wm * 64 + ((lane >> 4) << 2);
    const int ec = wn * 64 + (lane & 15);
    #pragma unroll
    for (int i = 0; i < 4; ++i) {
        #pragma unroll
        for (int reg = 0; reg < 4; ++reg) {
            const int grow = r0 + er + i * 16 + reg;
            if (grow >= M) continue;
            #pragma unroll
            for (int j = 0; j < 4; ++j) {
                const int cj = col0 + ec + j * 16;   // global W col (bias idx)
                const int cl = cj - cshift;          // local C col
                const float val = acc[i][j][reg];
                if constexpr (EPI == 0) {
                    ((u16*)CoutV)[(size_t)grow * ldc + cl] = f2bf(val);
                } else if constexpr (EPI == 1) {
                    ((float*)CoutV)[(size_t)grow * ldc + cl] += val;
                } else if constexpr (EPI == 2) {
                    ((u16*)CoutV)[(size_t)(rowbase + grow) * ldc + cl] =
                        f2bf(gelu_f(val + bias[cj]));
                } else if constexpr (EPI == 3) {
                    ((float*)CoutV)[(size_t)(rowbase + grow) * ldc + cl] =
                        val + bias[cj];
                } else {
                    ((float*)CoutV)[(size_t)(rowbase + grow) * ldc + cl] += val;
                }
            }
        }
    }
}

// ---------------------------------------------------------------------------
// Wave attention, one block per (b, head). qkv fused bf16 (row stride 768).
// ---------------------------------------------------------------------------
__global__ __launch_bounds__(256)
void attn_kernel(const u16* __restrict__ qkv, u16* __restrict__ o,
                 const float* __restrict__ wfreq, const float* __restrict__ wphase)
{
    const int bh = blockIdx.x;
    const int b  = bh >> 3;
    const int hh = bh & 7;

    __shared__ float ks[L_][DK_];
    __shared__ float vs[L_][DK_];
    __shared__ float wave[L_];

    const int tid = threadIdx.x;
    const long qbase = (long)b * L_ * 768 + hh * DK_;

    #pragma unroll
    for (int l = 0; l < 16; ++l) {
        int e = tid + l * 256;
        int row = e >> 5, dk = e & 31;
        ks[row][dk] = bf2f(qkv[qbase + 256 + (long)row * 768 + dk]);
        vs[row][dk] = bf2f(qkv[qbase + 512 + (long)row * 768 + dk]);
    }
    if (tid < L_) {
        float f2 = 6.2831853071795864769f * wfreq[hh];
        wave[tid] = cosf(f2 * (float)tid + wphase[hh]);
    }

    const int r = tid >> 1, half = tid & 1;
    float qr[32];
    {
        const ushort4* qp = (const ushort4*)(qkv + qbase + (long)r * 768);
        #pragma unroll
        for (int i4 = 0; i4 < 8; ++i4) {
            ushort4 t4 = qp[i4];
            qr[4*i4+0] = bf2f(t4.x); qr[4*i4+1] = bf2f(t4.y);
            qr[4*i4+2] = bf2f(t4.z); qr[4*i4+3] = bf2f(t4.w);
        }
    }
    __syncthreads();

    const float scale = 0.17677669529663687f;   // 1/sqrt(32)
    const int cbase = half * 64;

    float m = -1e30f;
    for (int cc = 0; cc < 64; ++cc) {
        int c = cbase + cc;
        float s = 0.0f;
        const float4* krow = (const float4*)&ks[c][0];
        #pragma unroll
        for (int i4 = 0; i4 < 8; ++i4) {
            float4 k4 = krow[i4];
            s = fmaf(qr[4*i4+0], k4.x, s);
            s = fmaf(qr[4*i4+1], k4.y, s);
            s = fmaf(qr[4*i4+2], k4.z, s);
            s = fmaf(qr[4*i4+3], k4.w, s);
        }
        s = s * scale * wave[c];
        m = fmaxf(m, s);
    }
    m = fmaxf(m, __shfl_xor(m, 1));

    float lsum = 0.0f;
    float O[32];
    #pragma unroll
    for (int i = 0; i < 32; ++i) O[i] = 0.0f;
    for (int cc = 0; cc < 64; ++cc) {
        int c = cbase + cc;
        float s = 0.0f;
        const float4* krow = (const float4*)&ks[c][0];
        #pragma unroll
        for (int i4 = 0; i4 < 8; ++i4) {
            float4 k4 = krow[i4];
            s = fmaf(qr[4*i4+0], k4.x, s);
            s = fmaf(qr[4*i4+1], k4.y, s);
            s = fmaf(qr[4*i4+2], k4.z, s);
            s = fmaf(qr[4*i4+3], k4.w, s);
        }
        s = s * scale * wave[c];
        float e = expf(s - m);
        lsum += e;
        const float4* vrow = (const float4*)&vs[c][0];
        #pragma unroll
        for (int i4 = 0; i4 < 8; ++i4) {
            float4 v4 = vrow[i4];
            O[4*i4+0] = fmaf(e, v4.x, O[4*i4+0]);
            O[4*i4+1] = fmaf(e, v4.y, O[4*i4+1]);
            O[4*i4+2] = fmaf(e, v4.z, O[4*i4+2]);
            O[4*i4+3] = fmaf(e, v4.w, O[4*i4+3]);
        }
    }
    lsum += __shfl_xor(lsum, 1);
    const float inv = 1.0f / lsum;

    const long obase = (long)b * L_ * D_ + hh * DK_;
    #pragma unroll
    for (int j = 0; j < 16; ++j) {
        float a0 = O[j]      + __shfl_xor(O[j], 1);
        float a1 = O[16 + j] + __shfl_xor(O[16 + j], 1);
        float val = (half ? a1 : a0) * inv;
        o[obase + (long)r * D_ + half * 16 + j] = f2bf(val);
    }
}

// ---------------------------------------------------------------------------
// MoE router (all f32)
// ---------------------------------------------------------------------------
__global__ __launch_bounds__(256)
void router_kernel(const float* __restrict__ h, const float* __restrict__ rtw,
                   const float* __restrict__ rtb, int* __restrict__ te,
                   float* __restrict__ twt, int* __restrict__ cnt)
{
    const int t = blockIdx.x * 256 + threadIdx.x;
    float lg[NE_];
    #pragma unroll
    for (int e = 0; e < NE_; ++e) lg[e] = rtb[e];
    const float4* rp = (const float4*)rtw;
    const float* hr = h + (long)t * D_;
    for (int d = 0; d < D_; ++d) {
        float xv = hr[d];
        float4 wa = rp[d * 2 + 0];
        float4 wb = rp[d * 2 + 1];
        lg[0] = fmaf(xv, wa.x, lg[0]);
        lg[1] = fmaf(xv, wa.y, lg[1]);
        lg[2] = fmaf(xv, wa.z, lg[2]);
        lg[3] = fmaf(xv, wa.w, lg[3]);
        lg[4] = fmaf(xv, wb.x, lg[4]);
        lg[5] = fmaf(xv, wb.y, lg[5]);
        lg[6] = fmaf(xv, wb.z, lg[6]);
        lg[7] = fmaf(xv, wb.w, lg[7]);
    }
    int i1 = 0; float v1 = lg[0];
    #pragma unroll
    for (int e = 1; e < NE_; ++e) { if (lg[e] > v1) { v1 = lg[e]; i1 = e; } }
    int i2 = (i1 == 0) ? 1 : 0; float v2 = lg[i2];
    #pragma unroll
    for (int e = 0; e < NE_; ++e) {
        if (e != i1 && lg[e] > v2) { v2 = lg[e]; i2 = e; }
    }
    float r   = expf(v2 - v1);
    float wa1 = 1.0f / (1.0f + r);
    float wa2 = r * wa1;
    te[2 * t]     = i1;
    te[2 * t + 1] = i2;
    twt[2 * t]     = wa1;
    twt[2 * t + 1] = wa2;
    atomicAdd(&cnt[i1], 1);
    atomicAdd(&cnt[i2], 1);
}

__global__ void zero8_kernel(int* cnt) {
    if (threadIdx.x < NE_) cnt[threadIdx.x] = 0;
}

__global__ void scan_kernel(const int* __restrict__ cnt, int* __restrict__ base_,
                            int* __restrict__ cursor)
{
    if (threadIdx.x == 0) {
        int a = 0;
        for (int e = 0; e < NE_; ++e) { base_[e] = a; a += cnt[e]; }
        base_[NE_] = a;
    }
    if (threadIdx.x < NE_) cursor[threadIdx.x] = 0;
}

__global__ __launch_bounds__(256)
void scatter_kernel(const int* __restrict__ te, const int* __restrict__ base_,
                    int* __restrict__ cursor, int* __restrict__ atok,
                    int* __restrict__ tslot)
{
    const int t = blockIdx.x * 256 + threadIdx.x;
    #pragma unroll
    for (int kk = 0; kk < 2; ++kk) {
        int e = te[2 * t + kk];
        int pos = atomicAdd(&cursor[e], 1);
        int slot = base_[e] + pos;
        atok[slot] = t;
        tslot[2 * t + kk] = slot;
    }
}

// h[t][d] += twt[2t]*eo[tslot[2t]][d] + twt[2t+1]*eo[tslot[2t+1]][d]
__global__ __launch_bounds__(256)
void combine_kernel(float* __restrict__ h, const float* __restrict__ eo,
                    const float* __restrict__ twt, const int* __restrict__ tslot)
{
    const int t = blockIdx.x;
    const int d = threadIdx.x;
    const int s0 = tslot[2 * t], s1 = tslot[2 * t + 1];
    const float w0 = twt[2 * t], w1 = twt[2 * t + 1];
    h[(long)t * D_ + d] += w0 * eo[(long)s0 * D_ + d] + w1 * eo[(long)s1 * D_ + d];
}

// ---------------------------------------------------------------------------
// Final: LN on last-position tokens, pred / softplus heads. f32 output.
// ---------------------------------------------------------------------------
__global__ __launch_bounds__(256)
void final_kernel(const float* __restrict__ h, const float* __restrict__ ln_g,
                  const float* __restrict__ ln_b, const float* __restrict__ pred_w,
                  const float* __restrict__ pred_b, const float* __restrict__ unc_w,
                  const float* __restrict__ unc_b, float* __restrict__ out)
{
    const int b = blockIdx.x;
    const int d = threadIdx.x;
    const long t = (long)b * L_ + (L_ - 1);
    const float val = h[t * D_ + d];

    __shared__ float red[4];
    __shared__ float lat[D_];

    float s = val;
    #pragma unroll
    for (int off = 32; off > 0; off >>= 1) s += __shfl_down(s, off);
    if ((d & 63) == 0) red[d >> 6] = s;
    __syncthreads();
    const float mean = (red[0] + red[1] + red[2] + red[3]) * (1.0f / D_);
    __syncthreads();

    const float dv = val - mean;
    s = dv * dv;
    #pragma unroll
    for (int off = 32; off > 0; off >>= 1) s += __shfl_down(s, off);
    if ((d & 63) == 0) red[d >> 6] = s;
    __syncthreads();
    const float var = (red[0] + red[1] + red[2] + red[3]) * (1.0f / D_);

    lat[d] = dv * rsqrtf(var + 1e-5f) * ln_g[d] + ln_b[d];
    __syncthreads();

    if (d < 2 * NOUT_) {
        const int j = d % NOUT_;
        const int sel = d / NOUT_;
        const float* w  = sel ? unc_w : pred_w;
        const float* bb = sel ? unc_b : pred_b;
        float acc = bb[j];
        for (int dd = 0; dd < D_; ++dd)
            acc = fmaf(lat[dd], w[dd * NOUT_ + j], acc);
        if (sel) acc = log1pf(expf(acc));
        out[sel * (B_ * NOUT_) + b * NOUT_ + j] = acc;
    }
}

// ---------------------------------------------------------------------------
extern "C" void kernel_launch(void* const* d_in, const int* in_sizes, int n_in,
                              void* d_out, int out_size, void* d_ws, size_t ws_size,
                              hipStream_t stream)
{
    (void)in_sizes; (void)n_in; (void)out_size; (void)ws_size;

    char* ws = (char*)d_ws;
    size_t off = 0;
    auto alloc = [&](size_t bytes) {
        size_t cur = off;
        off += (bytes + 255) & ~(size_t)255;
        return (void*)(ws + cur);
    };
    float* cs     = (float*)alloc((size_t)NSMALL * 4);                 //  0.6 MB
    u16*   qkvt   = (u16*)  alloc((size_t)NL_ * 768 * 256 * 2);        //  2.4 MB
    u16*   wot    = (u16*)  alloc((size_t)NL_ * 256 * 256 * 2);        //  0.8 MB
    u16*   ew1t   = (u16*)  alloc((size_t)3 * NE_ * DFF_ * D_ * 2);    // 12.6 MB
    u16*   ew2t   = (u16*)  alloc((size_t)3 * NE_ * D_ * DFF_ * 2);    // 12.6 MB
    float* h      = (float*)alloc((size_t)T_ * D_ * 4);                // 16.8 MB
    u16*   qkvb   = (u16*)  alloc((size_t)T_ * 768 * 2);               // 25.2 MB
    u16*   ob     = (u16*)  alloc((size_t)T_ * D_ * 2);                //  8.4 MB
    u16*   hidden = (u16*)  alloc((size_t)2 * T_ * CH_ * 2);           // 33.6 MB
    float* eo     = (float*)alloc((size_t)2 * T_ * D_ * 4);            // 33.6 MB
    int*   te     = (int*)  alloc((size_t)2 * T_ * 4);
    float* twt    = (float*)alloc((size_t)2 * T_ * 4);
    int*   atok   = (int*)  alloc((size_t)2 * T_ * 4);
    int*   tslot  = (int*)  alloc((size_t)2 * T_ * 4);
    int*   cnt    = (int*)  alloc(64 * 4);
    int*   base_  = (int*)  alloc(64 * 4);
    int*   cursor = (int*)  alloc(64 * 4);

    SrcPtrs P;
    for (int i = 0; i < 21; ++i) P.p[i] = d_in[i];
    const u16* probe = (const u16*)d_in[15];

    conv_small_kernel<<<(NSMALL + 255) / 256, 256, 0, stream>>>(P, cs);
    // weight transposes -> bf16 W^T
    transpose_kernel<256,256><<<(NL_*65536 + 255)/256, 256, 0, stream>>>(
        d_in[3], probe, qkvt, 768L*256, 0,   NL_*65536);
    transpose_kernel<256,256><<<(NL_*65536 + 255)/256, 256, 0, stream>>>(
        d_in[4], probe, qkvt, 768L*256, 256, NL_*65536);
    transpose_kernel<256,256><<<(NL_*65536 + 255)/256, 256, 0, stream>>>(
        d_in[5], probe, qkvt, 768L*256, 512, NL_*65536);
    transpose_kernel<256,256><<<(NL_*65536 + 255)/256, 256, 0, stream>>>(
        d_in[6], probe, wot, 65536L, 0, NL_*65536);
    transpose_kernel<256,1024><<<(24*262144 + 255)/256, 256, 0, stream>>>(
        d_in[11], probe, ew1t, 262144L, 0, 24*262144);
    transpose_kernel<1024,256><<<(24*262144 + 255)/256, 256, 0, stream>>>(
        d_in[13], probe, ew2t, 262144L, 0, 24*262144);

    const float* x      = cs;
    const float* emb_w  = cs + 98304;
    const float* emb_b  = cs + 99840;
    const float* wfreq  = cs + 100096;
    const float* wphase = cs + 100144;
    const float* rtw    = cs + 100192;
    const float* rtb    = cs + 106336;
    const float* eb1    = cs + 106360;
    const float* eb2    = cs + 130936;
    const float* ln_g   = cs + 137080;
    const float* ln_b   = cs + 137336;
    const float* pred_w = cs + 137592;
    const float* pred_b = cs + 138872;
    const float* unc_w  = cs + 138877;
    const float* unc_b  = cs + 140157;

    embed_kernel<<<(T_ * D_) / 256, 256, 0, stream>>>(x, emb_w, emb_b, h);

    for (int i = 0; i < NL_; ++i) {
        // fused QKV: [T,256] @ W^T[768,256] -> qkvb [T,768] bf16
        mfma_gemm<0, false, float><<<dim3(T_/128, 6, 1), 256, 0, stream>>>(
            h, D_, D_, qkvt + (size_t)i * 768 * 256, 0, 256, 0,
            nullptr, 0, qkvb, 768, 0, T_, nullptr, nullptr, nullptr);
        attn_kernel<<<B_ * H_, 256, 0, stream>>>(qkvb, ob,
                                                 wfreq + i * H_, wphase + i * H_);
        // o-proj accumulate into residual h
        mfma_gemm<1, false, u16><<<dim3(T_/128, 2, 1), 256, 0, stream>>>(
            ob, D_, D_, wot + (size_t)i * 65536, 0, 256, 0,
            nullptr, 0, h, D_, 0, T_, nullptr, nullptr, nullptr);

        if (i % 2 == 0) {
            const int m = i / 2;
            const u16* w1t = ew1t + (size_t)m * NE_ * DFF_ * D_;
            const u16* w2t = ew2t + (size_t)m * NE_ * D_ * DFF_;
            const float* b1 = eb1 + (size_t)m * NE_ * DFF_;
            const float* b2 = eb2 + (size_t)m * NE_ * D_;
            zero8_kernel<<<1, 64, 0, stream>>>(cnt);
            router_kernel<<<T_ / 256, 256, 0, stream>>>(
                h, rtw + (size_t)m * D_ * NE_, rtb + m * NE_, te, twt, cnt);
            scan_kernel<<<1, 64, 0, stream>>>(cnt, base_, cursor);
            scatter_kernel<<<T_ / 256, 256, 0, stream>>>(te, base_, cursor,
                                                         atok, tslot);
            for (int c = 0; c < DFF_ / CH_; ++c) {
                // w1 chunk: gathered h rows, bias+gelu -> bf16 hidden
                mfma_gemm<2, true, float><<<dim3(128, CH_/128, NE_), 256, 0, stream>>>(
                    h, D_, D_, w1t, (long)DFF_ * D_, 256, 0,
                    b1, DFF_, hidden, CH_, c * CH_,
                    0, cnt, base_, atok);
                // w2 chunk: hidden @ W2^T chunk -> eo (store+bias / accumulate)
                if (c == 0)
                    mfma_gemm<3, false, u16><<<dim3(128, 2, NE_), 256, 0, stream>>>(
                        hidden, CH_, CH_, w2t, (long)D_ * DFF_, DFF_, c * CH_,
                        b2, D_, eo, D_, 0,
                        0, cnt, base_, nullptr);
                else
                    mfma_gemm<4, false, u16><<<dim3(128, 2, NE_), 256, 0, stream>>>(
                        hidden, CH_, CH_, w2t, (long)D_ * DFF_, DFF_, c * CH_,
                        nullptr, 0, eo, D_, 0,
                        0, cnt, base_, nullptr);
            }
            combine_kernel<<<T_, 256, 0, stream>>>(h, eo, twt, tslot);
        }
    }

    final_kernel<<<B_, 256, 0, stream>>>(h, ln_g, ln_b, pred_w, pred_b,
                                         unc_w, unc_b, (float*)d_out);
}

// Round 7
// 1673.395 us; speedup vs baseline: 3.4961x; 1.4191x over previous
//
#include <hip/hip_runtime.h>
#include <hip/hip_bf16.h>
#include <math.h>

#define B_    128
#define L_    128
#define DIN   6
#define D_    256
#define H_    8
#define NL_   6
#define NE_   8
#define DFF_  1024
#define NOUT_ 5
#define T_    (B_*L_)      /* 16384 tokens */
#define DK_   32
#define CH_   512          /* DFF chunk for MoE hidden buffer */

typedef unsigned short u16;
typedef __hip_bfloat16 bf16;
typedef __attribute__((ext_vector_type(8))) short short8;
typedef __attribute__((ext_vector_type(8))) unsigned short ushort8v;
typedef __attribute__((ext_vector_type(4))) float floatx4;

// small f32 canon region: x, emb_w, emb_b, wfreq, wphase, rtw, rtb, eb1,
// eb2, ln_g, ln_b, pred_w, pred_b, unc_w, unc_b
__device__ const int S_PRE[16] = {
    0, 98304, 99840, 100096, 100144, 100192, 106336, 106360,
    130936, 137080, 137336, 137592, 138872, 138877, 140157, 140162};
__device__ const int S_SRC[15] = {0,1,2,7,8,9,10,12,14,15,16,17,18,19,20};
#define NSMALL 140162

struct SrcPtrs { const void* p[21]; };

__device__ __forceinline__ float bf2f(u16 u) {
    return __uint_as_float(((unsigned)u) << 16);
}
__device__ __forceinline__ u16 f2bf(float f) {
    union { bf16 b; u16 u; } c; c.b = __float2bfloat16(f); return c.u;
}
__device__ __forceinline__ float gelu_f(float x) {
    return 0.5f * x * (1.0f + erff(x * 0.70710678118654752f));
}

// ---------------------------------------------------------------------------
// Canonicalize small tensors to f32 (dtype probe: ln_g[0]==0x3F80 iff bf16)
// ---------------------------------------------------------------------------
__global__ __launch_bounds__(256)
void conv_small_kernel(SrcPtrs P, float* __restrict__ dst)
{
    const int i = blockIdx.x * 256 + threadIdx.x;
    if (i >= NSMALL) return;
    int seg = 0;
    #pragma unroll
    for (int s = 1; s < 15; ++s) seg += (i >= S_PRE[s]) ? 1 : 0;
    const int off = i - S_PRE[seg];
    const void* src = P.p[S_SRC[seg]];
    const bool isbf = (((const u16*)P.p[15])[0] == 0x3F80);
    if (isbf) dst[i] = bf2f(((const u16*)src)[off]);
    else      dst[i] = ((const float*)src)[off];
}

// ---------------------------------------------------------------------------
// Weight transpose+cast: dst[z][(n+noff)][k] (bf16, row len KD) = src[z][k][n]
// ---------------------------------------------------------------------------
template<int KD, int ND>
__global__ __launch_bounds__(256)
void transpose_kernel(const void* __restrict__ src, const u16* __restrict__ probe,
                      u16* __restrict__ dst, long dzs, int noff, int total)
{
    const int i = blockIdx.x * 256 + threadIdx.x;
    if (i >= total) return;
    const int z   = i / (KD * ND);
    const int rem = i - z * (KD * ND);
    const int n   = rem / KD;
    const int k   = rem - n * KD;
    const size_t si = (size_t)z * KD * ND + (size_t)k * ND + n;
    const bool isbf = (probe[0] == 0x3F80);
    const float v = isbf ? bf2f(((const u16*)src)[si]) : ((const float*)src)[si];
    dst[(size_t)z * dzs + (size_t)(n + noff) * KD + k] = f2bf(v);
}

// ---------------------------------------------------------------------------
// Embedding (all f32)
// ---------------------------------------------------------------------------
__global__ __launch_bounds__(256)
void embed_kernel(const float* __restrict__ x, const float* __restrict__ emb_w,
                  const float* __restrict__ emb_b, float* __restrict__ h)
{
    const int idx = blockIdx.x * 256 + threadIdx.x;
    const int t = idx >> 8;
    const int d = idx & 255;
    float acc = emb_b[d];
    #pragma unroll
    for (int j = 0; j < DIN; ++j)
        acc += x[t * DIN + j] * emb_w[j * D_ + d];
    h[idx] = acc;
}

// ---------------------------------------------------------------------------
// MFMA GEMM, 128x128 tile, 4 waves (each 64x64 via 16x16x32 bf16 MFMA).
// A: row-major MxK (f32 or bf16), staged->bf16 LDS.  W: bf16 W^T [N][K].
// EPI 0: store bf16 C            (fused QKV)
// EPI 1: C f32 +=                (o-proj residual)
// EPI 2: +bias, gelu -> bf16 at slot row (MoE w1)
// EPI 3: +bias -> f32 store at slot row  (MoE w2 chunk 0)
// EPI 4: f32 += at slot row              (MoE w2 chunk 1)
// GATHER: A row = atok[ebase[z] + row]
// ---------------------------------------------------------------------------
template<int EPI, bool GATHER, typename AT>
__global__ __launch_bounds__(256)
void mfma_gemm(const AT* __restrict__ A, int lda, int K,
               const u16* __restrict__ Wt, long wzs, int ldwt, int wkoff,
               const float* __restrict__ biasb, long bzs,
               void* __restrict__ CoutV, int ldc, int cshift,
               int Mfixed,
               const int* __restrict__ cnt, const int* __restrict__ ebase,
               const int* __restrict__ atok)
{
    const int z  = blockIdx.z;
    const int M  = cnt ? cnt[z] : Mfixed;
    const int r0 = blockIdx.x * 128;
    if (r0 >= M) return;
    const int rowbase = ebase ? ebase[z] : 0;
    const u16*   W    = Wt + (size_t)z * wzs;
    const float* bias = biasb ? (biasb + (size_t)z * bzs) : nullptr;
    const int col0 = blockIdx.y * 128 + cshift;

    __shared__ __attribute__((aligned(16))) u16 As[128][40];
    __shared__ __attribute__((aligned(16))) u16 Bs[128][40];
    __shared__ int stok[128];

    const int tid  = threadIdx.x;
    const int lane = tid & 63;
    const int wave = tid >> 6;
    const int wm = wave & 1, wn = wave >> 1;

    if (GATHER) {
        if (tid < 128) {
            int rr = r0 + tid;
            stok[tid] = (rr < M) ? atok[rowbase + rr] : 0;
        }
        __syncthreads();
    }

    floatx4 acc[4][4];
    #pragma unroll
    for (int i = 0; i < 4; ++i)
        #pragma unroll
        for (int j = 0; j < 4; ++j)
            acc[i][j] = (floatx4){0.f, 0.f, 0.f, 0.f};

    const int sr = tid >> 1;
    const int sk = (tid & 1) * 16;
    long arow;
    if (GATHER) arow = (long)stok[sr];
    else {
        int rr = r0 + sr; if (rr >= M) rr = M - 1;
        arow = (long)rowbase + rr;
    }
    const AT*  aptr = A + arow * (long)lda + sk;
    const u16* wptr = W + (size_t)(col0 + sr) * ldwt + wkoff + sk;

    const int fm = wm * 64 + (lane & 15);
    const int fn = wn * 64 + (lane & 15);
    const int fk = (lane >> 4) * 8;

    for (int k0 = 0; k0 < K; k0 += 32) {
        if constexpr (sizeof(AT) == 4) {
            const float4* ap = (const float4*)(aptr + k0);
            float4 v0 = ap[0], v1 = ap[1], v2 = ap[2], v3 = ap[3];
            ushort8v t0, t1;
            t0[0]=f2bf(v0.x); t0[1]=f2bf(v0.y); t0[2]=f2bf(v0.z); t0[3]=f2bf(v0.w);
            t0[4]=f2bf(v1.x); t0[5]=f2bf(v1.y); t0[6]=f2bf(v1.z); t0[7]=f2bf(v1.w);
            t1[0]=f2bf(v2.x); t1[1]=f2bf(v2.y); t1[2]=f2bf(v2.z); t1[3]=f2bf(v2.w);
            t1[4]=f2bf(v3.x); t1[5]=f2bf(v3.y); t1[6]=f2bf(v3.z); t1[7]=f2bf(v3.w);
            *(ushort8v*)&As[sr][sk]     = t0;
            *(ushort8v*)&As[sr][sk + 8] = t1;
        } else {
            const ushort8v* ap = (const ushort8v*)(aptr + k0);
            *(ushort8v*)&As[sr][sk]     = ap[0];
            *(ushort8v*)&As[sr][sk + 8] = ap[1];
        }
        {
            const ushort8v* wp = (const ushort8v*)(wptr + k0);
            *(ushort8v*)&Bs[sr][sk]     = wp[0];
            *(ushort8v*)&Bs[sr][sk + 8] = wp[1];
        }
        __syncthreads();

        short8 af[4], bfr[4];
        #pragma unroll
        for (int i = 0; i < 4; ++i) af[i]  = *(const short8*)&As[fm + 16*i][fk];
        #pragma unroll
        for (int j = 0; j < 4; ++j) bfr[j] = *(const short8*)&Bs[fn + 16*j][fk];
        #pragma unroll
        for (int i = 0; i < 4; ++i)
            #pragma unroll
            for (int j = 0; j < 4; ++j)
                acc[i][j] = __builtin_amdgcn_mfma_f32_16x16x32_bf16(
                    af[i], bfr[j], acc[i][j], 0, 0, 0);
        __syncthreads();
    }

    const int er = wm * 64 + ((lane >> 4) << 2);
    const int ec = wn * 64 + (lane & 15);
    #pragma unroll
    for (int i = 0; i < 4; ++i) {
        #pragma unroll
        for (int reg = 0; reg < 4; ++reg) {
            const int grow = r0 + er + i * 16 + reg;
            if (grow >= M) continue;
            #pragma unroll
            for (int j = 0; j < 4; ++j) {
                const int cj = col0 + ec + j * 16;
                const int cl = cj - cshift;
                const float val = acc[i][j][reg];
                if constexpr (EPI == 0) {
                    ((u16*)CoutV)[(size_t)grow * ldc + cl] = f2bf(val);
                } else if constexpr (EPI == 1) {
                    ((float*)CoutV)[(size_t)grow * ldc + cl] += val;
                } else if constexpr (EPI == 2) {
                    ((u16*)CoutV)[(size_t)(rowbase + grow) * ldc + cl] =
                        f2bf(gelu_f(val + bias[cj]));
                } else if constexpr (EPI == 3) {
                    ((float*)CoutV)[(size_t)(rowbase + grow) * ldc + cl] =
                        val + bias[cj];
                } else {
                    ((float*)CoutV)[(size_t)(rowbase + grow) * ldc + cl] += val;
                }
            }
        }
    }
}

// ---------------------------------------------------------------------------
// Wave attention, one block per (b, head). qkv fused bf16 (row stride 768).
// ---------------------------------------------------------------------------
__global__ __launch_bounds__(256)
void attn_kernel(const u16* __restrict__ qkv, u16* __restrict__ o,
                 const float* __restrict__ wfreq, const float* __restrict__ wphase)
{
    const int bh = blockIdx.x;
    const int b  = bh >> 3;
    const int hh = bh & 7;

    __shared__ float ks[L_][DK_];
    __shared__ float vs[L_][DK_];
    __shared__ float wave[L_];

    const int tid = threadIdx.x;
    const long qbase = (long)b * L_ * 768 + hh * DK_;

    #pragma unroll
    for (int l = 0; l < 16; ++l) {
        int e = tid + l * 256;
        int row = e >> 5, dk = e & 31;
        ks[row][dk] = bf2f(qkv[qbase + 256 + (long)row * 768 + dk]);
        vs[row][dk] = bf2f(qkv[qbase + 512 + (long)row * 768 + dk]);
    }
    if (tid < L_) {
        float f2 = 6.2831853071795864769f * wfreq[hh];
        wave[tid] = cosf(f2 * (float)tid + wphase[hh]);
    }

    const int r = tid >> 1, half = tid & 1;
    float qr[32];
    {
        const ushort4* qp = (const ushort4*)(qkv + qbase + (long)r * 768);
        #pragma unroll
        for (int i4 = 0; i4 < 8; ++i4) {
            ushort4 t4 = qp[i4];
            qr[4*i4+0] = bf2f(t4.x); qr[4*i4+1] = bf2f(t4.y);
            qr[4*i4+2] = bf2f(t4.z); qr[4*i4+3] = bf2f(t4.w);
        }
    }
    __syncthreads();

    const float scale = 0.17677669529663687f;   // 1/sqrt(32)
    const int cbase = half * 64;

    float m = -1e30f;
    for (int cc = 0; cc < 64; ++cc) {
        int c = cbase + cc;
        float s = 0.0f;
        const float4* krow = (const float4*)&ks[c][0];
        #pragma unroll
        for (int i4 = 0; i4 < 8; ++i4) {
            float4 k4 = krow[i4];
            s = fmaf(qr[4*i4+0], k4.x, s);
            s = fmaf(qr[4*i4+1], k4.y, s);
            s = fmaf(qr[4*i4+2], k4.z, s);
            s = fmaf(qr[4*i4+3], k4.w, s);
        }
        s = s * scale * wave[c];
        m = fmaxf(m, s);
    }
    m = fmaxf(m, __shfl_xor(m, 1));

    float lsum = 0.0f;
    float O[32];
    #pragma unroll
    for (int i = 0; i < 32; ++i) O[i] = 0.0f;
    for (int cc = 0; cc < 64; ++cc) {
        int c = cbase + cc;
        float s = 0.0f;
        const float4* krow = (const float4*)&ks[c][0];
        #pragma unroll
        for (int i4 = 0; i4 < 8; ++i4) {
            float4 k4 = krow[i4];
            s = fmaf(qr[4*i4+0], k4.x, s);
            s = fmaf(qr[4*i4+1], k4.y, s);
            s = fmaf(qr[4*i4+2], k4.z, s);
            s = fmaf(qr[4*i4+3], k4.w, s);
        }
        s = s * scale * wave[c];
        float e = expf(s - m);
        lsum += e;
        const float4* vrow = (const float4*)&vs[c][0];
        #pragma unroll
        for (int i4 = 0; i4 < 8; ++i4) {
            float4 v4 = vrow[i4];
            O[4*i4+0] = fmaf(e, v4.x, O[4*i4+0]);
            O[4*i4+1] = fmaf(e, v4.y, O[4*i4+1]);
            O[4*i4+2] = fmaf(e, v4.z, O[4*i4+2]);
            O[4*i4+3] = fmaf(e, v4.w, O[4*i4+3]);
        }
    }
    lsum += __shfl_xor(lsum, 1);
    const float inv = 1.0f / lsum;

    const long obase = (long)b * L_ * D_ + hh * DK_;
    #pragma unroll
    for (int j = 0; j < 16; ++j) {
        float a0 = O[j]      + __shfl_xor(O[j], 1);
        float a1 = O[16 + j] + __shfl_xor(O[16 + j], 1);
        float val = (half ? a1 : a0) * inv;
        o[obase + (long)r * D_ + half * 16 + j] = f2bf(val);
    }
}

// ---------------------------------------------------------------------------
// MoE router: one WAVE per token. Coalesced float4 h loads, butterfly
// logit reduction, lane 0 writes top-2. No global atomics.
// ---------------------------------------------------------------------------
__global__ __launch_bounds__(256)
void router_kernel(const float* __restrict__ h, const float* __restrict__ rtw,
                   const float* __restrict__ rtb, int* __restrict__ te,
                   float* __restrict__ twt)
{
    const int tid  = threadIdx.x;
    const int lane = tid & 63;
    const int wv   = tid >> 6;
    const int t    = blockIdx.x * 4 + wv;

    const float4 hv = ((const float4*)(h + (long)t * D_))[lane];
    const float4* rp = (const float4*)rtw;   // [256][8] f32 -> 2 float4 per d

    float lg[NE_];
    #pragma unroll
    for (int e = 0; e < NE_; ++e) lg[e] = 0.0f;
    #pragma unroll
    for (int i = 0; i < 4; ++i) {
        const int d = lane * 4 + i;
        const float xv = (i == 0) ? hv.x : (i == 1) ? hv.y : (i == 2) ? hv.z : hv.w;
        float4 wa = rp[d * 2 + 0];
        float4 wb = rp[d * 2 + 1];
        lg[0] = fmaf(xv, wa.x, lg[0]);
        lg[1] = fmaf(xv, wa.y, lg[1]);
        lg[2] = fmaf(xv, wa.z, lg[2]);
        lg[3] = fmaf(xv, wa.w, lg[3]);
        lg[4] = fmaf(xv, wb.x, lg[4]);
        lg[5] = fmaf(xv, wb.y, lg[5]);
        lg[6] = fmaf(xv, wb.z, lg[6]);
        lg[7] = fmaf(xv, wb.w, lg[7]);
    }
    #pragma unroll
    for (int off = 1; off < 64; off <<= 1)
        #pragma unroll
        for (int e = 0; e < NE_; ++e)
            lg[e] += __shfl_xor(lg[e], off);

    if (lane == 0) {
        #pragma unroll
        for (int e = 0; e < NE_; ++e) lg[e] += rtb[e];
        int i1 = 0; float v1 = lg[0];
        #pragma unroll
        for (int e = 1; e < NE_; ++e) { if (lg[e] > v1) { v1 = lg[e]; i1 = e; } }
        int i2 = (i1 == 0) ? 1 : 0; float v2 = lg[i2];
        #pragma unroll
        for (int e = 0; e < NE_; ++e) {
            if (e != i1 && lg[e] > v2) { v2 = lg[e]; i2 = e; }
        }
        float r   = expf(v2 - v1);
        float wa1 = 1.0f / (1.0f + r);
        te[2 * t]     = i1;
        te[2 * t + 1] = i2;
        twt[2 * t]     = wa1;
        twt[2 * t + 1] = r * wa1;
    }
}

// ---------------------------------------------------------------------------
// Count experts + exclusive scan + zero cursors, single block of 512.
// ---------------------------------------------------------------------------
__global__ __launch_bounds__(512)
void countscan_kernel(const int* __restrict__ te, int* __restrict__ cnt,
                      int* __restrict__ base_, int* __restrict__ cursor)
{
    const int tid = threadIdx.x;
    int c[NE_];
    #pragma unroll
    for (int e = 0; e < NE_; ++e) c[e] = 0;
    for (int i = tid; i < 2 * T_; i += 512) {
        const int e = te[i];
        #pragma unroll
        for (int ee = 0; ee < NE_; ++ee) c[ee] += (e == ee) ? 1 : 0;
    }
    #pragma unroll
    for (int off = 1; off < 64; off <<= 1)
        #pragma unroll
        for (int e = 0; e < NE_; ++e)
            c[e] += __shfl_xor(c[e], off);

    __shared__ int wsum[8][NE_];
    const int lane = tid & 63, wv = tid >> 6;
    if (lane == 0)
        #pragma unroll
        for (int e = 0; e < NE_; ++e) wsum[wv][e] = c[e];
    __syncthreads();
    if (tid == 0) {
        int a = 0;
        for (int e = 0; e < NE_; ++e) {
            int s = 0;
            for (int w = 0; w < 8; ++w) s += wsum[w][e];
            cnt[e] = s;
            base_[e] = a;
            a += s;
        }
    }
    if (tid < NE_) cursor[tid] = 0;
}

// ---------------------------------------------------------------------------
// Scatter with LDS rank aggregation: 8 global atomics per block.
// entry i (0..2T): token = i>>1.
// ---------------------------------------------------------------------------
__global__ __launch_bounds__(256)
void scatter_kernel(const int* __restrict__ te, const int* __restrict__ base_,
                    int* __restrict__ cursor, int* __restrict__ atok,
                    int* __restrict__ tslot)
{
    __shared__ int lcnt[NE_];
    __shared__ int gb[NE_];
    const int tid = threadIdx.x;
    if (tid < NE_) lcnt[tid] = 0;
    __syncthreads();

    const int i0 = blockIdx.x * 512 + tid * 2;
    const int e0 = te[i0], e1 = te[i0 + 1];
    const int r0 = atomicAdd(&lcnt[e0], 1);
    const int r1 = atomicAdd(&lcnt[e1], 1);
    __syncthreads();
    if (tid < NE_) gb[tid] = atomicAdd(&cursor[tid], lcnt[tid]);
    __syncthreads();

    const int s0 = base_[e0] + gb[e0] + r0;
    const int s1 = base_[e1] + gb[e1] + r1;
    atok[s0] = i0 >> 1;
    atok[s1] = i0 >> 1;
    tslot[i0]     = s0;
    tslot[i0 + 1] = s1;
}

// h[t][d] += twt[2t]*eo[tslot[2t]][d] + twt[2t+1]*eo[tslot[2t+1]][d]
__global__ __launch_bounds__(256)
void combine_kernel(float* __restrict__ h, const float* __restrict__ eo,
                    const float* __restrict__ twt, const int* __restrict__ tslot)
{
    const int t = blockIdx.x;
    const int d = threadIdx.x;
    const int s0 = tslot[2 * t], s1 = tslot[2 * t + 1];
    const float w0 = twt[2 * t], w1 = twt[2 * t + 1];
    h[(long)t * D_ + d] += w0 * eo[(long)s0 * D_ + d] + w1 * eo[(long)s1 * D_ + d];
}

// ---------------------------------------------------------------------------
// Final: LN on last-position tokens, pred / softplus heads. f32 output.
// ---------------------------------------------------------------------------
__global__ __launch_bounds__(256)
void final_kernel(const float* __restrict__ h, const float* __restrict__ ln_g,
                  const float* __restrict__ ln_b, const float* __restrict__ pred_w,
                  const float* __restrict__ pred_b, const float* __restrict__ unc_w,
                  const float* __restrict__ unc_b, float* __restrict__ out)
{
    const int b = blockIdx.x;
    const int d = threadIdx.x;
    const long t = (long)b * L_ + (L_ - 1);
    const float val = h[t * D_ + d];

    __shared__ float red[4];
    __shared__ float lat[D_];

    float s = val;
    #pragma unroll
    for (int off = 32; off > 0; off >>= 1) s += __shfl_down(s, off);
    if ((d & 63) == 0) red[d >> 6] = s;
    __syncthreads();
    const float mean = (red[0] + red[1] + red[2] + red[3]) * (1.0f / D_);
    __syncthreads();

    const float dv = val - mean;
    s = dv * dv;
    #pragma unroll
    for (int off = 32; off > 0; off >>= 1) s += __shfl_down(s, off);
    if ((d & 63) == 0) red[d >> 6] = s;
    __syncthreads();
    const float var = (red[0] + red[1] + red[2] + red[3]) * (1.0f / D_);

    lat[d] = dv * rsqrtf(var + 1e-5f) * ln_g[d] + ln_b[d];
    __syncthreads();

    if (d < 2 * NOUT_) {
        const int j = d % NOUT_;
        const int sel = d / NOUT_;
        const float* w  = sel ? unc_w : pred_w;
        const float* bb = sel ? unc_b : pred_b;
        float acc = bb[j];
        for (int dd = 0; dd < D_; ++dd)
            acc = fmaf(lat[dd], w[dd * NOUT_ + j], acc);
        if (sel) acc = log1pf(expf(acc));
        out[sel * (B_ * NOUT_) + b * NOUT_ + j] = acc;
    }
}

// ---------------------------------------------------------------------------
extern "C" void kernel_launch(void* const* d_in, const int* in_sizes, int n_in,
                              void* d_out, int out_size, void* d_ws, size_t ws_size,
                              hipStream_t stream)
{
    (void)in_sizes; (void)n_in; (void)out_size; (void)ws_size;

    char* ws = (char*)d_ws;
    size_t off = 0;
    auto alloc = [&](size_t bytes) {
        size_t cur = off;
        off += (bytes + 255) & ~(size_t)255;
        return (void*)(ws + cur);
    };
    float* cs     = (float*)alloc((size_t)NSMALL * 4);
    u16*   qkvt   = (u16*)  alloc((size_t)NL_ * 768 * 256 * 2);
    u16*   wot    = (u16*)  alloc((size_t)NL_ * 256 * 256 * 2);
    u16*   ew1t   = (u16*)  alloc((size_t)3 * NE_ * DFF_ * D_ * 2);
    u16*   ew2t   = (u16*)  alloc((size_t)3 * NE_ * D_ * DFF_ * 2);
    float* h      = (float*)alloc((size_t)T_ * D_ * 4);
    u16*   qkvb   = (u16*)  alloc((size_t)T_ * 768 * 2);
    u16*   ob     = (u16*)  alloc((size_t)T_ * D_ * 2);
    u16*   hidden = (u16*)  alloc((size_t)2 * T_ * CH_ * 2);
    float* eo     = (float*)alloc((size_t)2 * T_ * D_ * 4);
    int*   te     = (int*)  alloc((size_t)2 * T_ * 4);
    float* twt    = (float*)alloc((size_t)2 * T_ * 4);
    int*   atok   = (int*)  alloc((size_t)2 * T_ * 4);
    int*   tslot  = (int*)  alloc((size_t)2 * T_ * 4);
    int*   cnt    = (int*)  alloc(64 * 4);
    int*   base_  = (int*)  alloc(64 * 4);
    int*   cursor = (int*)  alloc(64 * 4);

    SrcPtrs P;
    for (int i = 0; i < 21; ++i) P.p[i] = d_in[i];
    const u16* probe = (const u16*)d_in[15];

    conv_small_kernel<<<(NSMALL + 255) / 256, 256, 0, stream>>>(P, cs);
    transpose_kernel<256,256><<<(NL_*65536 + 255)/256, 256, 0, stream>>>(
        d_in[3], probe, qkvt, 768L*256, 0,   NL_*65536);
    transpose_kernel<256,256><<<(NL_*65536 + 255)/256, 256, 0, stream>>>(
        d_in[4], probe, qkvt, 768L*256, 256, NL_*65536);
    transpose_kernel<256,256><<<(NL_*65536 + 255)/256, 256, 0, stream>>>(
        d_in[5], probe, qkvt, 768L*256, 512, NL_*65536);
    transpose_kernel<256,256><<<(NL_*65536 + 255)/256, 256, 0, stream>>>(
        d_in[6], probe, wot, 65536L, 0, NL_*65536);
    transpose_kernel<256,1024><<<(24*262144 + 255)/256, 256, 0, stream>>>(
        d_in[11], probe, ew1t, 262144L, 0, 24*262144);
    transpose_kernel<1024,256><<<(24*262144 + 255)/256, 256, 0, stream>>>(
        d_in[13], probe, ew2t, 262144L, 0, 24*262144);

    const float* x      = cs;
    const float* emb_w  = cs + 98304;
    const float* emb_b  = cs + 99840;
    const float* wfreq  = cs + 100096;
    const float* wphase = cs + 100144;
    const float* rtw    = cs + 100192;
    const float* rtb    = cs + 106336;
    const float* eb1    = cs + 106360;
    const float* eb2    = cs + 130936;
    const float* ln_g   = cs + 137080;
    const float* ln_b   = cs + 137336;
    const float* pred_w = cs + 137592;
    const float* pred_b = cs + 138872;
    const float* unc_w  = cs + 138877;
    const float* unc_b  = cs + 140157;

    embed_kernel<<<(T_ * D_) / 256, 256, 0, stream>>>(x, emb_w, emb_b, h);

    for (int i = 0; i < NL_; ++i) {
        mfma_gemm<0, false, float><<<dim3(T_/128, 6, 1), 256, 0, stream>>>(
            h, D_, D_, qkvt + (size_t)i * 768 * 256, 0, 256, 0,
            nullptr, 0, qkvb, 768, 0, T_, nullptr, nullptr, nullptr);
        attn_kernel<<<B_ * H_, 256, 0, stream>>>(qkvb, ob,
                                                 wfreq + i * H_, wphase + i * H_);
        mfma_gemm<1, false, u16><<<dim3(T_/128, 2, 1), 256, 0, stream>>>(
            ob, D_, D_, wot + (size_t)i * 65536, 0, 256, 0,
            nullptr, 0, h, D_, 0, T_, nullptr, nullptr, nullptr);

        if (i % 2 == 0) {
            const int m = i / 2;
            const u16* w1t = ew1t + (size_t)m * NE_ * DFF_ * D_;
            const u16* w2t = ew2t + (size_t)m * NE_ * D_ * DFF_;
            const float* b1 = eb1 + (size_t)m * NE_ * DFF_;
            const float* b2 = eb2 + (size_t)m * NE_ * D_;
            router_kernel<<<T_ / 4, 256, 0, stream>>>(
                h, rtw + (size_t)m * D_ * NE_, rtb + m * NE_, te, twt);
            countscan_kernel<<<1, 512, 0, stream>>>(te, cnt, base_, cursor);
            scatter_kernel<<<(2 * T_) / 512, 256, 0, stream>>>(te, base_, cursor,
                                                               atok, tslot);
            for (int c = 0; c < DFF_ / CH_; ++c) {
                mfma_gemm<2, true, float><<<dim3(128, CH_/128, NE_), 256, 0, stream>>>(
                    h, D_, D_, w1t, (long)DFF_ * D_, 256, 0,
                    b1, DFF_, hidden, CH_, c * CH_,
                    0, cnt, base_, atok);
                if (c == 0)
                    mfma_gemm<3, false, u16><<<dim3(128, 2, NE_), 256, 0, stream>>>(
                        hidden, CH_, CH_, w2t, (long)D_ * DFF_, DFF_, c * CH_,
                        b2, D_, eo, D_, 0,
                        0, cnt, base_, nullptr);
                else
                    mfma_gemm<4, false, u16><<<dim3(128, 2, NE_), 256, 0, stream>>>(
                        hidden, CH_, CH_, w2t, (long)D_ * DFF_, DFF_, c * CH_,
                        nullptr, 0, eo, D_, 0,
                        0, cnt, base_, nullptr);
            }
            combine_kernel<<<T_, 256, 0, stream>>>(h, eo, twt, tslot);
        }
    }

    final_kernel<<<B_, 256, 0, stream>>>(h, ln_g, ln_b, pred_w, pred_b,
                                         unc_w, unc_b, (float*)d_out);
}

// Round 8
// 1200.548 us; speedup vs baseline: 4.8730x; 1.3939x over previous
//
#include <hip/hip_runtime.h>
#include <hip/hip_bf16.h>
#include <math.h>

#define B_    128
#define L_    128
#define DIN   6
#define D_    256
#define H_    8
#define NL_   6
#define NE_   8
#define DFF_  1024
#define NOUT_ 5
#define T_    (B_*L_)      /* 16384 tokens */
#define DK_   32
#define CH_   512          /* DFF chunk for MoE hidden buffer */

typedef unsigned short u16;
typedef __hip_bfloat16 bf16;
typedef __attribute__((ext_vector_type(8))) short short8;
typedef __attribute__((ext_vector_type(8))) unsigned short ushort8v;
typedef __attribute__((ext_vector_type(4))) float floatx4;

// small f32 canon region: x, emb_w, emb_b, wfreq, wphase, rtw, rtb, eb1,
// eb2, ln_g, ln_b, pred_w, pred_b, unc_w, unc_b
__device__ const int S_PRE[16] = {
    0, 98304, 99840, 100096, 100144, 100192, 106336, 106360,
    130936, 137080, 137336, 137592, 138872, 138877, 140157, 140162};
__device__ const int S_SRC[15] = {0,1,2,7,8,9,10,12,14,15,16,17,18,19,20};
#define NSMALL 140162

struct SrcPtrs { const void* p[21]; };

__device__ __forceinline__ float bf2f(u16 u) {
    return __uint_as_float(((unsigned)u) << 16);
}
__device__ __forceinline__ u16 f2bf(float f) {
    union { bf16 b; u16 u; } c; c.b = __float2bfloat16(f); return c.u;
}
__device__ __forceinline__ float gelu_f(float x) {
    return 0.5f * x * (1.0f + erff(x * 0.70710678118654752f));
}

// ---------------------------------------------------------------------------
// Canonicalize small tensors to f32 (dtype probe: ln_g[0]==0x3F80 iff bf16)
// ---------------------------------------------------------------------------
__global__ __launch_bounds__(256)
void conv_small_kernel(SrcPtrs P, float* __restrict__ dst)
{
    const int i = blockIdx.x * 256 + threadIdx.x;
    if (i >= NSMALL) return;
    int seg = 0;
    #pragma unroll
    for (int s = 1; s < 15; ++s) seg += (i >= S_PRE[s]) ? 1 : 0;
    const int off = i - S_PRE[seg];
    const void* src = P.p[S_SRC[seg]];
    const bool isbf = (((const u16*)P.p[15])[0] == 0x3F80);
    if (isbf) dst[i] = bf2f(((const u16*)src)[off]);
    else      dst[i] = ((const float*)src)[off];
}

// ---------------------------------------------------------------------------
// Weight transpose+cast: dst[z][(n+noff)][k] (bf16, row len KD) = src[z][k][n]
// ---------------------------------------------------------------------------
template<int KD, int ND>
__global__ __launch_bounds__(256)
void transpose_kernel(const void* __restrict__ src, const u16* __restrict__ probe,
                      u16* __restrict__ dst, long dzs, int noff, int total)
{
    const int i = blockIdx.x * 256 + threadIdx.x;
    if (i >= total) return;
    const int z   = i / (KD * ND);
    const int rem = i - z * (KD * ND);
    const int n   = rem / KD;
    const int k   = rem - n * KD;
    const size_t si = (size_t)z * KD * ND + (size_t)k * ND + n;
    const bool isbf = (probe[0] == 0x3F80);
    const float v = isbf ? bf2f(((const u16*)src)[si]) : ((const float*)src)[si];
    dst[(size_t)z * dzs + (size_t)(n + noff) * KD + k] = f2bf(v);
}

// ---------------------------------------------------------------------------
// Embedding (all f32)
// ---------------------------------------------------------------------------
__global__ __launch_bounds__(256)
void embed_kernel(const float* __restrict__ x, const float* __restrict__ emb_w,
                  const float* __restrict__ emb_b, float* __restrict__ h)
{
    const int idx = blockIdx.x * 256 + threadIdx.x;
    const int t = idx >> 8;
    const int d = idx & 255;
    float acc = emb_b[d];
    #pragma unroll
    for (int j = 0; j < DIN; ++j)
        acc += x[t * DIN + j] * emb_w[j * D_ + d];
    h[idx] = acc;
}

// ---------------------------------------------------------------------------
// MFMA GEMM, 128x128 tile, 4 waves (each 64x64 via 16x16x32 bf16 MFMA).
// A: row-major MxK (f32 or bf16), staged->bf16 LDS.  W: bf16 W^T [N][K].
// EPI 0: store bf16 C            (fused QKV)
// EPI 1: C f32 +=                (o-proj residual)
// EPI 2: +bias, gelu -> bf16 at slot row (MoE w1)
// EPI 3: +bias -> f32 store at slot row  (MoE w2 chunk 0)
// EPI 4: f32 += at slot row              (MoE w2 chunk 1)
// GATHER: A row = atok[ebase[z] + row]
// ---------------------------------------------------------------------------
template<int EPI, bool GATHER, typename AT>
__global__ __launch_bounds__(256)
void mfma_gemm(const AT* __restrict__ A, int lda, int K,
               const u16* __restrict__ Wt, long wzs, int ldwt, int wkoff,
               const float* __restrict__ biasb, long bzs,
               void* __restrict__ CoutV, int ldc, int cshift,
               int Mfixed,
               const int* __restrict__ cnt, const int* __restrict__ ebase,
               const int* __restrict__ atok)
{
    const int z  = blockIdx.z;
    const int M  = cnt ? cnt[z] : Mfixed;
    const int r0 = blockIdx.x * 128;
    if (r0 >= M) return;
    const int rowbase = ebase ? ebase[z] : 0;
    const u16*   W    = Wt + (size_t)z * wzs;
    const float* bias = biasb ? (biasb + (size_t)z * bzs) : nullptr;
    const int col0 = blockIdx.y * 128 + cshift;

    __shared__ __attribute__((aligned(16))) u16 As[128][40];
    __shared__ __attribute__((aligned(16))) u16 Bs[128][40];
    __shared__ int stok[128];

    const int tid  = threadIdx.x;
    const int lane = tid & 63;
    const int wave = tid >> 6;
    const int wm = wave & 1, wn = wave >> 1;

    if (GATHER) {
        if (tid < 128) {
            int rr = r0 + tid;
            stok[tid] = (rr < M) ? atok[rowbase + rr] : 0;
        }
        __syncthreads();
    }

    floatx4 acc[4][4];
    #pragma unroll
    for (int i = 0; i < 4; ++i)
        #pragma unroll
        for (int j = 0; j < 4; ++j)
            acc[i][j] = (floatx4){0.f, 0.f, 0.f, 0.f};

    const int sr = tid >> 1;
    const int sk = (tid & 1) * 16;
    long arow;
    if (GATHER) arow = (long)stok[sr];
    else {
        int rr = r0 + sr; if (rr >= M) rr = M - 1;
        arow = (long)rowbase + rr;
    }
    const AT*  aptr = A + arow * (long)lda + sk;
    const u16* wptr = W + (size_t)(col0 + sr) * ldwt + wkoff + sk;

    const int fm = wm * 64 + (lane & 15);
    const int fn = wn * 64 + (lane & 15);
    const int fk = (lane >> 4) * 8;

    for (int k0 = 0; k0 < K; k0 += 32) {
        if constexpr (sizeof(AT) == 4) {
            const float4* ap = (const float4*)(aptr + k0);
            float4 v0 = ap[0], v1 = ap[1], v2 = ap[2], v3 = ap[3];
            ushort8v t0, t1;
            t0[0]=f2bf(v0.x); t0[1]=f2bf(v0.y); t0[2]=f2bf(v0.z); t0[3]=f2bf(v0.w);
            t0[4]=f2bf(v1.x); t0[5]=f2bf(v1.y); t0[6]=f2bf(v1.z); t0[7]=f2bf(v1.w);
            t1[0]=f2bf(v2.x); t1[1]=f2bf(v2.y); t1[2]=f2bf(v2.z); t1[3]=f2bf(v2.w);
            t1[4]=f2bf(v3.x); t1[5]=f2bf(v3.y); t1[6]=f2bf(v3.z); t1[7]=f2bf(v3.w);
            *(ushort8v*)&As[sr][sk]     = t0;
            *(ushort8v*)&As[sr][sk + 8] = t1;
        } else {
            const ushort8v* ap = (const ushort8v*)(aptr + k0);
            *(ushort8v*)&As[sr][sk]     = ap[0];
            *(ushort8v*)&As[sr][sk + 8] = ap[1];
        }
        {
            const ushort8v* wp = (const ushort8v*)(wptr + k0);
            *(ushort8v*)&Bs[sr][sk]     = wp[0];
            *(ushort8v*)&Bs[sr][sk + 8] = wp[1];
        }
        __syncthreads();

        short8 af[4], bfr[4];
        #pragma unroll
        for (int i = 0; i < 4; ++i) af[i]  = *(const short8*)&As[fm + 16*i][fk];
        #pragma unroll
        for (int j = 0; j < 4; ++j) bfr[j] = *(const short8*)&Bs[fn + 16*j][fk];
        #pragma unroll
        for (int i = 0; i < 4; ++i)
            #pragma unroll
            for (int j = 0; j < 4; ++j)
                acc[i][j] = __builtin_amdgcn_mfma_f32_16x16x32_bf16(
                    af[i], bfr[j], acc[i][j], 0, 0, 0);
        __syncthreads();
    }

    const int er = wm * 64 + ((lane >> 4) << 2);
    const int ec = wn * 64 + (lane & 15);
    #pragma unroll
    for (int i = 0; i < 4; ++i) {
        #pragma unroll
        for (int reg = 0; reg < 4; ++reg) {
            const int grow = r0 + er + i * 16 + reg;
            if (grow >= M) continue;
            #pragma unroll
            for (int j = 0; j < 4; ++j) {
                const int cj = col0 + ec + j * 16;
                const int cl = cj - cshift;
                const float val = acc[i][j][reg];
                if constexpr (EPI == 0) {
                    ((u16*)CoutV)[(size_t)grow * ldc + cl] = f2bf(val);
                } else if constexpr (EPI == 1) {
                    ((float*)CoutV)[(size_t)grow * ldc + cl] += val;
                } else if constexpr (EPI == 2) {
                    ((u16*)CoutV)[(size_t)(rowbase + grow) * ldc + cl] =
                        f2bf(gelu_f(val + bias[cj]));
                } else if constexpr (EPI == 3) {
                    ((float*)CoutV)[(size_t)(rowbase + grow) * ldc + cl] =
                        val + bias[cj];
                } else {
                    ((float*)CoutV)[(size_t)(rowbase + grow) * ldc + cl] += val;
                }
            }
        }
    }
}

// ---------------------------------------------------------------------------
// MFMA wave attention, one block (256 thr, 4 waves) per (b, head).
// S = Q K^T (128x128x32, 1 MFMA K-step per tile), scale*wave, full-row
// softmax in-wave, P -> LDS bf16, O = P V via V^T fragments.
// ---------------------------------------------------------------------------
__global__ __launch_bounds__(256)
void attn_kernel(const u16* __restrict__ qkv, u16* __restrict__ o,
                 const float* __restrict__ wfreq, const float* __restrict__ wphase)
{
    const int bh = blockIdx.x;
    const int b  = bh >> 3;
    const int hh = bh & 7;

    __shared__ __attribute__((aligned(16))) u16 Qs[128][40];
    __shared__ __attribute__((aligned(16))) u16 Ks[128][40];
    __shared__ __attribute__((aligned(16))) u16 Vt[32][136];
    __shared__ __attribute__((aligned(16))) u16 Ps[128][136];
    __shared__ float wavec[128];

    const int tid  = threadIdx.x;
    const int lane = tid & 63;
    const int w    = tid >> 6;
    const int col16 = lane & 15;
    const int quad  = lane >> 4;

    const long qbase = (long)b * L_ * 768 + hh * DK_;

    // stage Q, K, V^T (bf16)
    {
        const int row = tid >> 1;
        const int hf  = (tid & 1) * 16;
        const u16* src = qkv + qbase + (long)row * 768 + hf;
        *(ushort8v*)&Qs[row][hf]     = *(const ushort8v*)(src);
        *(ushort8v*)&Qs[row][hf + 8] = *(const ushort8v*)(src + 8);
        *(ushort8v*)&Ks[row][hf]     = *(const ushort8v*)(src + 256);
        *(ushort8v*)&Ks[row][hf + 8] = *(const ushort8v*)(src + 264);
        #pragma unroll
        for (int j = 0; j < 16; ++j)
            Vt[hf + j][row] = src[512 + j];
    }
    if (tid < L_) {
        float f2 = 6.2831853071795864769f * wfreq[hh];
        wavec[tid] = cosf(f2 * (float)tid + wphase[hh]);
    }
    __syncthreads();

    const float scale = 0.17677669529663687f;   // 1/sqrt(32)
    float wv8[8];
    #pragma unroll
    for (int ni = 0; ni < 8; ++ni)
        wv8[ni] = scale * wavec[ni * 16 + col16];

    // S = Q K^T : wave w owns rows [w*32, w*32+32)
    const int m0 = w * 32;
    floatx4 accs[2][8];
    {
        short8 a0 = *(const short8*)&Qs[m0 + col16][quad * 8];
        short8 a1 = *(const short8*)&Qs[m0 + 16 + col16][quad * 8];
        #pragma unroll
        for (int ni = 0; ni < 8; ++ni) {
            short8 bf = *(const short8*)&Ks[ni * 16 + col16][quad * 8];
            accs[0][ni] = __builtin_amdgcn_mfma_f32_16x16x32_bf16(
                a0, bf, (floatx4){0.f,0.f,0.f,0.f}, 0, 0, 0);
            accs[1][ni] = __builtin_amdgcn_mfma_f32_16x16x32_bf16(
                a1, bf, (floatx4){0.f,0.f,0.f,0.f}, 0, 0, 0);
        }
    }
    // scale * wave multiplier (column-dependent; col = lane&15 of n-tile)
    #pragma unroll
    for (int mi = 0; mi < 2; ++mi)
        #pragma unroll
        for (int ni = 0; ni < 8; ++ni)
            #pragma unroll
            for (int reg = 0; reg < 4; ++reg)
                accs[mi][ni][reg] *= wv8[ni];

    // full-row softmax: row = m0 + mi*16 + quad*4 + reg, in-wave
    #pragma unroll
    for (int mi = 0; mi < 2; ++mi) {
        #pragma unroll
        for (int reg = 0; reg < 4; ++reg) {
            float rmax = -1e30f;
            #pragma unroll
            for (int ni = 0; ni < 8; ++ni)
                rmax = fmaxf(rmax, accs[mi][ni][reg]);
            #pragma unroll
            for (int off = 1; off < 16; off <<= 1)
                rmax = fmaxf(rmax, __shfl_xor(rmax, off));
            float e[8], rsum = 0.0f;
            #pragma unroll
            for (int ni = 0; ni < 8; ++ni) {
                e[ni] = expf(accs[mi][ni][reg] - rmax);
                rsum += e[ni];
            }
            #pragma unroll
            for (int off = 1; off < 16; off <<= 1)
                rsum += __shfl_xor(rsum, off);
            const float inv = 1.0f / rsum;
            const int row = m0 + mi * 16 + quad * 4 + reg;
            #pragma unroll
            for (int ni = 0; ni < 8; ++ni)
                Ps[row][ni * 16 + col16] = f2bf(e[ni] * inv);
        }
    }
    __syncthreads();

    // O = P V : a-frags from Ps, b-frags from Vt (both k-contiguous)
    floatx4 acco[2][2];
    #pragma unroll
    for (int mi = 0; mi < 2; ++mi)
        #pragma unroll
        for (int nj = 0; nj < 2; ++nj)
            acco[mi][nj] = (floatx4){0.f,0.f,0.f,0.f};
    #pragma unroll
    for (int kk = 0; kk < 4; ++kk) {
        short8 a0 = *(const short8*)&Ps[m0 + col16][kk * 32 + quad * 8];
        short8 a1 = *(const short8*)&Ps[m0 + 16 + col16][kk * 32 + quad * 8];
        short8 b0 = *(const short8*)&Vt[col16][kk * 32 + quad * 8];
        short8 b1 = *(const short8*)&Vt[16 + col16][kk * 32 + quad * 8];
        acco[0][0] = __builtin_amdgcn_mfma_f32_16x16x32_bf16(a0, b0, acco[0][0], 0, 0, 0);
        acco[0][1] = __builtin_amdgcn_mfma_f32_16x16x32_bf16(a0, b1, acco[0][1], 0, 0, 0);
        acco[1][0] = __builtin_amdgcn_mfma_f32_16x16x32_bf16(a1, b0, acco[1][0], 0, 0, 0);
        acco[1][1] = __builtin_amdgcn_mfma_f32_16x16x32_bf16(a1, b1, acco[1][1], 0, 0, 0);
    }

    // write O: row = m0+mi*16+quad*4+reg, col = nj*16+col16 (head slice)
    const long obase = (long)b * L_ * D_ + hh * DK_;
    #pragma unroll
    for (int mi = 0; mi < 2; ++mi)
        #pragma unroll
        for (int reg = 0; reg < 4; ++reg) {
            const int row = m0 + mi * 16 + quad * 4 + reg;
            #pragma unroll
            for (int nj = 0; nj < 2; ++nj)
                o[obase + (long)row * D_ + nj * 16 + col16] =
                    f2bf(acco[mi][nj][reg]);
        }
}

// ---------------------------------------------------------------------------
// MoE router: one WAVE per token. Coalesced float4 h loads, butterfly
// logit reduction, lane 0 writes top-2. No global atomics.
// ---------------------------------------------------------------------------
__global__ __launch_bounds__(256)
void router_kernel(const float* __restrict__ h, const float* __restrict__ rtw,
                   const float* __restrict__ rtb, int* __restrict__ te,
                   float* __restrict__ twt)
{
    const int tid  = threadIdx.x;
    const int lane = tid & 63;
    const int wv   = tid >> 6;
    const int t    = blockIdx.x * 4 + wv;

    const float4 hv = ((const float4*)(h + (long)t * D_))[lane];
    const float4* rp = (const float4*)rtw;

    float lg[NE_];
    #pragma unroll
    for (int e = 0; e < NE_; ++e) lg[e] = 0.0f;
    #pragma unroll
    for (int i = 0; i < 4; ++i) {
        const int d = lane * 4 + i;
        const float xv = (i == 0) ? hv.x : (i == 1) ? hv.y : (i == 2) ? hv.z : hv.w;
        float4 wa = rp[d * 2 + 0];
        float4 wb = rp[d * 2 + 1];
        lg[0] = fmaf(xv, wa.x, lg[0]);
        lg[1] = fmaf(xv, wa.y, lg[1]);
        lg[2] = fmaf(xv, wa.z, lg[2]);
        lg[3] = fmaf(xv, wa.w, lg[3]);
        lg[4] = fmaf(xv, wb.x, lg[4]);
        lg[5] = fmaf(xv, wb.y, lg[5]);
        lg[6] = fmaf(xv, wb.z, lg[6]);
        lg[7] = fmaf(xv, wb.w, lg[7]);
    }
    #pragma unroll
    for (int off = 1; off < 64; off <<= 1)
        #pragma unroll
        for (int e = 0; e < NE_; ++e)
            lg[e] += __shfl_xor(lg[e], off);

    if (lane == 0) {
        #pragma unroll
        for (int e = 0; e < NE_; ++e) lg[e] += rtb[e];
        int i1 = 0; float v1 = lg[0];
        #pragma unroll
        for (int e = 1; e < NE_; ++e) { if (lg[e] > v1) { v1 = lg[e]; i1 = e; } }
        int i2 = (i1 == 0) ? 1 : 0; float v2 = lg[i2];
        #pragma unroll
        for (int e = 0; e < NE_; ++e) {
            if (e != i1 && lg[e] > v2) { v2 = lg[e]; i2 = e; }
        }
        float r   = expf(v2 - v1);
        float wa1 = 1.0f / (1.0f + r);
        te[2 * t]     = i1;
        te[2 * t + 1] = i2;
        twt[2 * t]     = wa1;
        twt[2 * t + 1] = r * wa1;
    }
}

// ---------------------------------------------------------------------------
// Count experts + exclusive scan + zero cursors, single block of 512.
// ---------------------------------------------------------------------------
__global__ __launch_bounds__(512)
void countscan_kernel(const int* __restrict__ te, int* __restrict__ cnt,
                      int* __restrict__ base_, int* __restrict__ cursor)
{
    const int tid = threadIdx.x;
    int c[NE_];
    #pragma unroll
    for (int e = 0; e < NE_; ++e) c[e] = 0;
    for (int i = tid; i < 2 * T_; i += 512) {
        const int e = te[i];
        #pragma unroll
        for (int ee = 0; ee < NE_; ++ee) c[ee] += (e == ee) ? 1 : 0;
    }
    #pragma unroll
    for (int off = 1; off < 64; off <<= 1)
        #pragma unroll
        for (int e = 0; e < NE_; ++e)
            c[e] += __shfl_xor(c[e], off);

    __shared__ int wsum[8][NE_];
    const int lane = tid & 63, wv = tid >> 6;
    if (lane == 0)
        #pragma unroll
        for (int e = 0; e < NE_; ++e) wsum[wv][e] = c[e];
    __syncthreads();
    if (tid == 0) {
        int a = 0;
        for (int e = 0; e < NE_; ++e) {
            int s = 0;
            for (int w = 0; w < 8; ++w) s += wsum[w][e];
            cnt[e] = s;
            base_[e] = a;
            a += s;
        }
    }
    if (tid < NE_) cursor[tid] = 0;
}

// ---------------------------------------------------------------------------
// Scatter with LDS rank aggregation: 8 global atomics per block.
// ---------------------------------------------------------------------------
__global__ __launch_bounds__(256)
void scatter_kernel(const int* __restrict__ te, const int* __restrict__ base_,
                    int* __restrict__ cursor, int* __restrict__ atok,
                    int* __restrict__ tslot)
{
    __shared__ int lcnt[NE_];
    __shared__ int gb[NE_];
    const int tid = threadIdx.x;
    if (tid < NE_) lcnt[tid] = 0;
    __syncthreads();

    const int i0 = blockIdx.x * 512 + tid * 2;
    const int e0 = te[i0], e1 = te[i0 + 1];
    const int r0 = atomicAdd(&lcnt[e0], 1);
    const int r1 = atomicAdd(&lcnt[e1], 1);
    __syncthreads();
    if (tid < NE_) gb[tid] = atomicAdd(&cursor[tid], lcnt[tid]);
    __syncthreads();

    const int s0 = base_[e0] + gb[e0] + r0;
    const int s1 = base_[e1] + gb[e1] + r1;
    atok[s0] = i0 >> 1;
    atok[s1] = i0 >> 1;
    tslot[i0]     = s0;
    tslot[i0 + 1] = s1;
}

// h[t][d] += twt[2t]*eo[tslot[2t]][d] + twt[2t+1]*eo[tslot[2t+1]][d]
__global__ __launch_bounds__(256)
void combine_kernel(float* __restrict__ h, const float* __restrict__ eo,
                    const float* __restrict__ twt, const int* __restrict__ tslot)
{
    const int t = blockIdx.x;
    const int d = threadIdx.x;
    const int s0 = tslot[2 * t], s1 = tslot[2 * t + 1];
    const float w0 = twt[2 * t], w1 = twt[2 * t + 1];
    h[(long)t * D_ + d] += w0 * eo[(long)s0 * D_ + d] + w1 * eo[(long)s1 * D_ + d];
}

// ---------------------------------------------------------------------------
// Final: LN on last-position tokens, pred / softplus heads. f32 output.
// ---------------------------------------------------------------------------
__global__ __launch_bounds__(256)
void final_kernel(const float* __restrict__ h, const float* __restrict__ ln_g,
                  const float* __restrict__ ln_b, const float* __restrict__ pred_w,
                  const float* __restrict__ pred_b, const float* __restrict__ unc_w,
                  const float* __restrict__ unc_b, float* __restrict__ out)
{
    const int b = blockIdx.x;
    const int d = threadIdx.x;
    const long t = (long)b * L_ + (L_ - 1);
    const float val = h[t * D_ + d];

    __shared__ float red[4];
    __shared__ float lat[D_];

    float s = val;
    #pragma unroll
    for (int off = 32; off > 0; off >>= 1) s += __shfl_down(s, off);
    if ((d & 63) == 0) red[d >> 6] = s;
    __syncthreads();
    const float mean = (red[0] + red[1] + red[2] + red[3]) * (1.0f / D_);
    __syncthreads();

    const float dv = val - mean;
    s = dv * dv;
    #pragma unroll
    for (int off = 32; off > 0; off >>= 1) s += __shfl_down(s, off);
    if ((d & 63) == 0) red[d >> 6] = s;
    __syncthreads();
    const float var = (red[0] + red[1] + red[2] + red[3]) * (1.0f / D_);

    lat[d] = dv * rsqrtf(var + 1e-5f) * ln_g[d] + ln_b[d];
    __syncthreads();

    if (d < 2 * NOUT_) {
        const int j = d % NOUT_;
        const int sel = d / NOUT_;
        const float* w  = sel ? unc_w : pred_w;
        const float* bb = sel ? unc_b : pred_b;
        float acc = bb[j];
        for (int dd = 0; dd < D_; ++dd)
            acc = fmaf(lat[dd], w[dd * NOUT_ + j], acc);
        if (sel) acc = log1pf(expf(acc));
        out[sel * (B_ * NOUT_) + b * NOUT_ + j] = acc;
    }
}

// ---------------------------------------------------------------------------
extern "C" void kernel_launch(void* const* d_in, const int* in_sizes, int n_in,
                              void* d_out, int out_size, void* d_ws, size_t ws_size,
                              hipStream_t stream)
{
    (void)in_sizes; (void)n_in; (void)out_size; (void)ws_size;

    char* ws = (char*)d_ws;
    size_t off = 0;
    auto alloc = [&](size_t bytes) {
        size_t cur = off;
        off += (bytes + 255) & ~(size_t)255;
        return (void*)(ws + cur);
    };
    float* cs     = (float*)alloc((size_t)NSMALL * 4);
    u16*   qkvt   = (u16*)  alloc((size_t)NL_ * 768 * 256 * 2);
    u16*   wot    = (u16*)  alloc((size_t)NL_ * 256 * 256 * 2);
    u16*   ew1t   = (u16*)  alloc((size_t)3 * NE_ * DFF_ * D_ * 2);
    u16*   ew2t   = (u16*)  alloc((size_t)3 * NE_ * D_ * DFF_ * 2);
    float* h      = (float*)alloc((size_t)T_ * D_ * 4);
    u16*   qkvb   = (u16*)  alloc((size_t)T_ * 768 * 2);
    u16*   ob     = (u16*)  alloc((size_t)T_ * D_ * 2);
    u16*   hidden = (u16*)  alloc((size_t)2 * T_ * CH_ * 2);
    float* eo     = (float*)alloc((size_t)2 * T_ * D_ * 4);
    int*   te     = (int*)  alloc((size_t)2 * T_ * 4);
    float* twt    = (float*)alloc((size_t)2 * T_ * 4);
    int*   atok   = (int*)  alloc((size_t)2 * T_ * 4);
    int*   tslot  = (int*)  alloc((size_t)2 * T_ * 4);
    int*   cnt    = (int*)  alloc(64 * 4);
    int*   base_  = (int*)  alloc(64 * 4);
    int*   cursor = (int*)  alloc(64 * 4);

    SrcPtrs P;
    for (int i = 0; i < 21; ++i) P.p[i] = d_in[i];
    const u16* probe = (const u16*)d_in[15];

    conv_small_kernel<<<(NSMALL + 255) / 256, 256, 0, stream>>>(P, cs);
    transpose_kernel<256,256><<<(NL_*65536 + 255)/256, 256, 0, stream>>>(
        d_in[3], probe, qkvt, 768L*256, 0,   NL_*65536);
    transpose_kernel<256,256><<<(NL_*65536 + 255)/256, 256, 0, stream>>>(
        d_in[4], probe, qkvt, 768L*256, 256, NL_*65536);
    transpose_kernel<256,256><<<(NL_*65536 + 255)/256, 256, 0, stream>>>(
        d_in[5], probe, qkvt, 768L*256, 512, NL_*65536);
    transpose_kernel<256,256><<<(NL_*65536 + 255)/256, 256, 0, stream>>>(
        d_in[6], probe, wot, 65536L, 0, NL_*65536);
    transpose_kernel<256,1024><<<(24*262144 + 255)/256, 256, 0, stream>>>(
        d_in[11], probe, ew1t, 262144L, 0, 24*262144);
    transpose_kernel<1024,256><<<(24*262144 + 255)/256, 256, 0, stream>>>(
        d_in[13], probe, ew2t, 262144L, 0, 24*262144);

    const float* x      = cs;
    const float* emb_w  = cs + 98304;
    const float* emb_b  = cs + 99840;
    const float* wfreq  = cs + 100096;
    const float* wphase = cs + 100144;
    const float* rtw    = cs + 100192;
    const float* rtb    = cs + 106336;
    const float* eb1    = cs + 106360;
    const float* eb2    = cs + 130936;
    const float* ln_g   = cs + 137080;
    const float* ln_b   = cs + 137336;
    const float* pred_w = cs + 137592;
    const float* pred_b = cs + 138872;
    const float* unc_w  = cs + 138877;
    const float* unc_b  = cs + 140157;

    embed_kernel<<<(T_ * D_) / 256, 256, 0, stream>>>(x, emb_w, emb_b, h);

    for (int i = 0; i < NL_; ++i) {
        mfma_gemm<0, false, float><<<dim3(T_/128, 6, 1), 256, 0, stream>>>(
            h, D_, D_, qkvt + (size_t)i * 768 * 256, 0, 256, 0,
            nullptr, 0, qkvb, 768, 0, T_, nullptr, nullptr, nullptr);
        attn_kernel<<<B_ * H_, 256, 0, stream>>>(qkvb, ob,
                                                 wfreq + i * H_, wphase + i * H_);
        mfma_gemm<1, false, u16><<<dim3(T_/128, 2, 1), 256, 0, stream>>>(
            ob, D_, D_, wot + (size_t)i * 65536, 0, 256, 0,
            nullptr, 0, h, D_, 0, T_, nullptr, nullptr, nullptr);

        if (i % 2 == 0) {
            const int m = i / 2;
            const u16* w1t = ew1t + (size_t)m * NE_ * DFF_ * D_;
            const u16* w2t = ew2t + (size_t)m * NE_ * D_ * DFF_;
            const float* b1 = eb1 + (size_t)m * NE_ * DFF_;
            const float* b2 = eb2 + (size_t)m * NE_ * D_;
            router_kernel<<<T_ / 4, 256, 0, stream>>>(
                h, rtw + (size_t)m * D_ * NE_, rtb + m * NE_, te, twt);
            countscan_kernel<<<1, 512, 0, stream>>>(te, cnt, base_, cursor);
            scatter_kernel<<<(2 * T_) / 512, 256, 0, stream>>>(te, base_, cursor,
                                                               atok, tslot);
            for (int c = 0; c < DFF_ / CH_; ++c) {
                mfma_gemm<2, true, float><<<dim3(128, CH_/128, NE_), 256, 0, stream>>>(
                    h, D_, D_, w1t, (long)DFF_ * D_, 256, 0,
                    b1, DFF_, hidden, CH_, c * CH_,
                    0, cnt, base_, atok);
                if (c == 0)
                    mfma_gemm<3, false, u16><<<dim3(128, 2, NE_), 256, 0, stream>>>(
                        hidden, CH_, CH_, w2t, (long)D_ * DFF_, DFF_, c * CH_,
                        b2, D_, eo, D_, 0,
                        0, cnt, base_, nullptr);
                else
                    mfma_gemm<4, false, u16><<<dim3(128, 2, NE_), 256, 0, stream>>>(
                        hidden, CH_, CH_, w2t, (long)D_ * DFF_, DFF_, c * CH_,
                        nullptr, 0, eo, D_, 0,
                        0, cnt, base_, nullptr);
            }
            combine_kernel<<<T_, 256, 0, stream>>>(h, eo, twt, tslot);
        }
    }

    final_kernel<<<B_, 256, 0, stream>>>(h, ln_g, ln_b, pred_w, pred_b,
                                         unc_w, unc_b, (float*)d_out);
}